// Round 11
// baseline (195.531 us; speedup 1.0000x reference)
//
#include <hip/hip_runtime.h>
#include <hip/hip_bf16.h>
#include <math.h>

#define NQ   2500
#define CDIM 256
#define NKV  5000
#define NH   8
#define DH   32
#define SPLITS 10
#define KPS   500          // keys per split
#define FULLT 7            // 7 full 64-key tiles
#define TILES 8            // 7 full + 1 tail
#define TAILNK 52          // 500 - 7*64
#define VF_SHORTS 1310720  // SPLITS*NH*TILES*2048

typedef __attribute__((ext_vector_type(8))) short bf16x8;
typedef __attribute__((ext_vector_type(4))) short short4v;
typedef __attribute__((ext_vector_type(4))) float f32x4;

#define MFMA __builtin_amdgcn_mfma_f32_16x16x32_bf16

__device__ __forceinline__ short f2bf(float f) {          // RNE
  union { float f; unsigned u; } v; v.f = f;
  unsigned r = v.u + 0x7FFFu + ((v.u >> 16) & 1u);
  return (short)(r >> 16);
}
__device__ __forceinline__ float bf2f(unsigned short s) {
  union { unsigned u; float f; } x; x.u = ((unsigned)s) << 16; return x.f;
}
__device__ __forceinline__ unsigned cvt_pk_bf16(float a, float b) { // [lo=a, hi=b] RNE
  unsigned r;
  asm("v_cvt_pk_bf16_f32 %0, %1, %2" : "=v"(r) : "v"(a), "v"(b));
  return r;
}
__device__ __forceinline__ float exp2_fast(float x) {
  float r; asm("v_exp_f32 %0, %1" : "=v"(r) : "v"(x)); return r;
}

// ============ fused prep: build_kv | transpose_img | prep_w | zero_Vf ============
// blocks [0,5000): kv | [5000,5168): imgT | [5168,5456): wf | [5456,8016): zero Vf
__global__ __launch_bounds__(256) void k_prep(
    const float* __restrict__ query, const float* __restrict__ prev,
    const float* __restrict__ ego, float* __restrict__ kv,
    const float* __restrict__ img, unsigned short* __restrict__ imgT,
    const float* __restrict__ inW, const float* __restrict__ moW,
    const float* __restrict__ scaW, const float* __restrict__ fW1,
    const float* __restrict__ fW2, short* __restrict__ wf,
    unsigned* __restrict__ VfU)
{
  const int gid = blockIdx.x, tid = threadIdx.x;
  if (gid < NKV) {
    const int row = gid, c = tid;
    if (row < NQ) { kv[(size_t)row*CDIM + c] = query[(size_t)row*CDIM + c]; return; }
    int n = row - NQ;
    float txm = ego[3], tym = ego[7];
    float yaw = atan2f(ego[4], ego[0]);
    float cs = cosf(yaw), sn = sinf(yaw);
    float dx = txm * (1.f/51.2f), dy = tym * (1.f/51.2f);
    int i = n / 50, j = n % 50;
    float gx = (2.f*j + 1.f)*(1.f/50.f) - 1.f;
    float gy = (2.f*i + 1.f)*(1.f/50.f) - 1.f;
    float px = cs*gx - sn*gy + dx;
    float py = sn*gx + cs*gy + dy;
    float xf = ((px + 1.f)*50.f - 1.f)*0.5f;
    float yf = ((py + 1.f)*50.f - 1.f)*0.5f;
    float x0f = floorf(xf), y0f = floorf(yf);
    int x0 = (int)x0f, y0 = (int)y0f;
    float wx = xf - x0f, wy = yf - y0f;
    float v00 = (x0  >=0 && x0  <50 && y0  >=0 && y0  <50) ? prev[((size_t)(y0*50+x0      ))*CDIM + c] : 0.f;
    float v10 = (x0+1>=0 && x0+1<50 && y0  >=0 && y0  <50) ? prev[((size_t)(y0*50+x0+1    ))*CDIM + c] : 0.f;
    float v01 = (x0  >=0 && x0  <50 && y0+1>=0 && y0+1<50) ? prev[((size_t)((y0+1)*50+x0  ))*CDIM + c] : 0.f;
    float v11 = (x0+1>=0 && x0+1<50 && y0+1>=0 && y0+1<50) ? prev[((size_t)((y0+1)*50+x0+1))*CDIM + c] : 0.f;
    float v = (v00*(1.f-wx) + v10*wx)*(1.f-wy) + (v01*(1.f-wx) + v11*wx)*wy;
    kv[(size_t)row*CDIM + c] = v;
    return;
  }
  if (gid < NKV + 168) {
    const int b = gid - NKV;          // n*28 + y
    const int n = b / 28, y = b % 28;
    const int c = tid;
    for (int x = 0; x < 50; ++x)
      imgT[((size_t)((n*28 + y)*50 + x))*CDIM + c] =
        (unsigned short)f2bf(img[((size_t)(n*CDIM + c)*28 + y)*50 + x]);
    return;
  }
  if (gid < NKV + 168 + 288) {
    // weight fragments: wf[obase + ((n>>4)*(K/8) + (k>>3))*128 + (n&15)*8 + j]
    const int id = (gid - NKV - 168)*256 + tid;
    if (id >= 73728) return;
    const int s = id*8;
    const float* src; int off, K, obase;
    if      (s < 65536)  { src = inW;          off = s;          K = 256; obase = 0; }
    else if (s < 131072) { src = inW + 65536;  off = s - 65536;  K = 256; obase = 65536; }
    else if (s < 196608) { src = inW + 131072; off = s - 131072; K = 256; obase = 131072; }
    else if (s < 262144) { src = moW;          off = s - 196608; K = 256; obase = 196608; }
    else if (s < 327680) { src = scaW;         off = s - 262144; K = 256; obase = 262144; }
    else if (s < 458752) { src = fW1;          off = s - 327680; K = 256; obase = 327680; }
    else                 { src = fW2;          off = s - 458752; K = 512; obase = 458752; }
    const int n = off / K, k = off - n*K;
    short4v lo, hi;
    #pragma unroll
    for (int j = 0; j < 4; ++j) { lo[j] = f2bf(src[off+j]); hi[j] = f2bf(src[off+4+j]); }
    short* dst = wf + obase + (size_t)((n>>4)*(K>>3) + (k>>3))*128 + (n&15)*8;
    *(short4v*)dst = lo;
    *(short4v*)(dst+4) = hi;
    return;
  }
  {
    // zero Vf (every call -> masked tail slots deterministic; valid slots
    // are overwritten by the QKV epilogue scatter before any read)
    const int id = (gid - NKV - 168 - 288)*256 + tid;   // 2560*256 = 655,360 exact
    VfU[id] = 0u;
  }
}

// ============ fused QKV GEMM: kv(5000x256) @ inW(768x256)^T + inb ============
// n0<256 -> Qbf (x qscale, rows<NQ); n0<512 -> Kbf; else Vf PV-fragments directly.
__global__ __launch_bounds__(256) void k_gemm_qkv(
    const float* __restrict__ A, const short* __restrict__ Wf,
    const float* __restrict__ bias, short* __restrict__ Qbf,
    short* __restrict__ Kbf, short* __restrict__ Vf, float qscale)
{
  __shared__ short Abf[8][33][8];
  const int tid = threadIdx.x;
  const int lane = tid & 63, wid = tid >> 6;
  const int wm = wid >> 1, wn = wid & 1;
  const int g = lane >> 4, c = lane & 15;
  const int m0 = blockIdx.y << 5, n0 = blockIdx.x << 6;
  if (n0 < 256 && m0 >= NQ) return;    // block-uniform early out
  const int srow = tid >> 3, skq = tid & 7;
  const short* wfa = Wf + (size_t)((n0 + wn*32) >> 4)       * 32 * 128 + c*8;
  const short* wfb = Wf + (size_t)(((n0 + wn*32) >> 4) + 1) * 32 * 128 + c*8;
  f32x4 acc0 = {0.f,0.f,0.f,0.f}, acc1 = acc0;
  for (int k0 = 0; k0 < 256; k0 += 64) {
    const float* ap = A + (size_t)(m0+srow)*256 + k0 + skq*8;
    const float4 fa0 = *(const float4*)ap;
    const float4 fa1 = *(const float4*)(ap+4);
    __syncthreads();
    union { unsigned u[4]; bf16x8 v; } pa;
    pa.u[0] = cvt_pk_bf16(fa0.x, fa0.y);  pa.u[1] = cvt_pk_bf16(fa0.z, fa0.w);
    pa.u[2] = cvt_pk_bf16(fa1.x, fa1.y);  pa.u[3] = cvt_pk_bf16(fa1.z, fa1.w);
    *(bf16x8*)&Abf[skq][srow][0] = pa.v;
    __syncthreads();
    #pragma unroll
    for (int s = 0; s < 2; ++s) {
      const int kq = (k0 >> 3) + s*4 + g;
      const bf16x8 fA  = *(const bf16x8*)&Abf[s*4+g][wm*16 + c][0];
      const bf16x8 fW0 = *(const bf16x8*)(wfa + (size_t)kq*128);
      const bf16x8 fW1 = *(const bf16x8*)(wfb + (size_t)kq*128);
      acc0 = MFMA(fA, fW0, acc0, 0,0,0);
      acc1 = MFMA(fA, fW1, acc1, 0,0,0);
    }
  }
  const int nc0 = n0 + wn*32 + c, nc1 = nc0 + 16;
  const float b0v = bias[nc0], b1v = bias[nc1];
  #pragma unroll
  for (int r = 0; r < 4; ++r) {
    const int m = m0 + wm*16 + g*4 + r;
    if (m >= NKV) continue;
    const float v0 = acc0[r] + b0v;
    const float v1 = acc1[r] + b1v;
    if (nc0 < 256) {
      if (m < NQ) {
        Qbf[(size_t)m*256 + nc0] = f2bf(v0*qscale);
        Qbf[(size_t)m*256 + nc1] = f2bf(v1*qscale);
      }
    } else if (nc0 < 512) {
      Kbf[(size_t)m*256 + nc0 - 256] = f2bf(v0);
      Kbf[(size_t)m*256 + nc1 - 256] = f2bf(v1);
    } else {
      // V -> PV fragments (proven round-10 mapping; tail slots pre-zeroed)
      const int d0 = nc0 - 512;
      const int hh = d0 >> 5;
      const int cc = d0 & 15;
      const int sp = m / KPS;
      const int kin = m - sp*KPS;
      const int t = kin >> 6, r6 = kin & 63;
      const int kt2 = r6 >> 5, ko32 = r6 & 31;
      const int gg = (ko32 >> 2) & 3;
      const int jj = ((ko32 >> 4) << 2) | (ko32 & 3);
      const size_t base = (((size_t)(sp*NH + hh)*TILES + t)*2 + kt2)*2;
      Vf[(base    )*512 + (gg*16 + cc)*8 + jj] = f2bf(v0);   // i=0: d 0-15
      Vf[(base + 1)*512 + (gg*16 + cc)*8 + jj] = f2bf(v1);   // i=1: d 16-31
    }
  }
}

// ---------------- generic MFMA GEMM (frag-W); amode 1 = A from combine(opart,mlp) ----
__global__ __launch_bounds__(256) void k_gemm(
    const float* __restrict__ A, const short* __restrict__ Wf,
    const float* __restrict__ bias, const float* __restrict__ res,
    float* __restrict__ C, short* __restrict__ Cb,
    const short* __restrict__ opart, const float* __restrict__ mlp,
    int M, int N, int K, int relu, int mode, int amode, float scale)
{
  __shared__ short Abf[8][33][8];
  const int tid = threadIdx.x;
  const int lane = tid & 63, wid = tid >> 6;
  const int wm = wid >> 1, wn = wid & 1;
  const int g = lane >> 4, c = lane & 15;
  const int m0 = blockIdx.y << 5, n0 = blockIdx.x << 6;
  const int srow = tid >> 3, skq = tid & 7;
  const int kb8 = K >> 3;
  const short* wfa = Wf + (size_t)((n0 + wn*32) >> 4)       * kb8 * 128 + c*8;
  const short* wfb = Wf + (size_t)(((n0 + wn*32) >> 4) + 1) * kb8 * 128 + c*8;
  f32x4 acc0 = {0.f,0.f,0.f,0.f}, acc1 = acc0;
  const float4 z4 = make_float4(0.f,0.f,0.f,0.f);
  for (int k0 = 0; k0 < K; k0 += 64) {
    float4 fa0 = z4, fa1 = z4;
    const int mrow = m0 + srow;
    if (mrow < M) {
      if (amode == 0) {
        const float* ap = A + (size_t)mrow*K + k0 + skq*8;
        fa0 = *(const float4*)ap; fa1 = *(const float4*)(ap+4);
      } else {
        // A[mrow][c0..c0+7] = combine(opart, mlp) on the fly (exp2 domain)
        const int c0 = k0 + skq*8;
        const int hh = c0 >> 5, dd = c0 & 31;
        float mstar = -INFINITY;
        float ms[SPLITS], ls[SPLITS];
        #pragma unroll
        for (int s = 0; s < SPLITS; ++s) {
          const size_t b = (size_t)(s*NH + hh)*NQ + mrow;
          ms[s] = mlp[b*2]; ls[s] = mlp[b*2+1];
          mstar = fmaxf(mstar, ms[s]);
        }
        float num[8] = {0,0,0,0,0,0,0,0};
        float den = 0.f;
        #pragma unroll
        for (int s = 0; s < SPLITS; ++s) {
          const float e = exp2_fast(ms[s] - mstar);
          den += ls[s]*e;
          const size_t b = (size_t)(s*NH + hh)*NQ + mrow;
          const short* op = opart + b*DH + dd;
          #pragma unroll
          for (int j = 0; j < 8; ++j) num[j] += bf2f((unsigned short)op[j])*e;
        }
        const float inv = 1.f/den;
        fa0.x = num[0]*inv; fa0.y = num[1]*inv; fa0.z = num[2]*inv; fa0.w = num[3]*inv;
        fa1.x = num[4]*inv; fa1.y = num[5]*inv; fa1.z = num[6]*inv; fa1.w = num[7]*inv;
      }
    }
    __syncthreads();
    union { unsigned u[4]; bf16x8 v; } pa;
    pa.u[0] = cvt_pk_bf16(fa0.x, fa0.y);  pa.u[1] = cvt_pk_bf16(fa0.z, fa0.w);
    pa.u[2] = cvt_pk_bf16(fa1.x, fa1.y);  pa.u[3] = cvt_pk_bf16(fa1.z, fa1.w);
    *(bf16x8*)&Abf[skq][srow][0] = pa.v;
    __syncthreads();
    #pragma unroll
    for (int s = 0; s < 2; ++s) {
      const int kq = (k0 >> 3) + s*4 + g;
      const bf16x8 fA  = *(const bf16x8*)&Abf[s*4+g][wm*16 + c][0];
      const bf16x8 fW0 = *(const bf16x8*)(wfa + (size_t)kq*128);
      const bf16x8 fW1 = *(const bf16x8*)(wfb + (size_t)kq*128);
      acc0 = MFMA(fA, fW0, acc0, 0,0,0);
      acc1 = MFMA(fA, fW1, acc1, 0,0,0);
    }
  }
  const int nc0 = n0 + wn*32 + c, nc1 = nc0 + 16;
  const float b0v = bias[nc0], b1v = bias[nc1];
  #pragma unroll
  for (int r = 0; r < 4; ++r) {
    const int m = m0 + wm*16 + g*4 + r;
    if (m >= M) continue;
    float v0 = acc0[r] + b0v;
    float v1 = acc1[r] + b1v;
    if (mode == 0) {
      if (res) { v0 += res[(size_t)m*N + nc0]; v1 += res[(size_t)m*N + nc1]; }
      if (relu) { v0 = fmaxf(v0, 0.f); v1 = fmaxf(v1, 0.f); }
      C[(size_t)m*N + nc0] = v0;
      C[(size_t)m*N + nc1] = v1;
    } else {
      Cb[(size_t)m*N + nc0] = f2bf(v0*scale);
      Cb[(size_t)m*N + nc1] = f2bf(v1*scale);
    }
  }
}

// ---------------- flash softmax+PV: defer-max, l via ones-MFMA, fused pack ----------------
__device__ __forceinline__ void softmax_pv(
    f32x4 s0, f32x4 s1, f32x4 s2, f32x4 s3, bool tail, int g,
    float& m, f32x4& lacc, f32x4& oA, f32x4& oB,
    bf16x8 A0lo, bf16x8 A0hi, bf16x8 A1lo, bf16x8 A1hi, bf16x8 ones)
{
  float sv[16];
  #pragma unroll
  for (int r=0;r<4;++r){ sv[r]=s0[r]; sv[4+r]=s1[r]; sv[8+r]=s2[r]; sv[12+r]=s3[r]; }
  if (tail) {
    #pragma unroll
    for (int i=0;i<16;++i) {
      const int kl = (i>>2)*16 + g*4 + (i&3);
      if (kl >= TAILNK) sv[i] = -1e30f;
    }
  }
  const float t0 = fmaxf(fmaxf(sv[0], sv[1]), sv[2]);
  const float t1 = fmaxf(fmaxf(sv[3], sv[4]), sv[5]);
  const float t2 = fmaxf(fmaxf(sv[6], sv[7]), sv[8]);
  const float t3 = fmaxf(fmaxf(sv[9], sv[10]), sv[11]);
  const float t4 = fmaxf(fmaxf(sv[12], sv[13]), sv[14]);
  const float mx = fmaxf(fmaxf(fmaxf(t0, t1), t2), fmaxf(fmaxf(t3, t4), sv[15]));
  if (!__all(mx <= m + 8.f)) {
    float mm = fmaxf(mx, __shfl_xor(mx, 16));
    mm = fmaxf(mm, __shfl_xor(mm, 32));
    const float mn = fmaxf(m, mm);
    const float scl = exp2_fast(m - mn);   // first tile: exp2(-inf)=0
    m = mn;
    lacc[0] *= scl;                        // only [0] is ever read
    #pragma unroll
    for (int r=0;r<4;++r){ oA[r]*=scl; oB[r]*=scl; }
  }
  union { unsigned u[4]; bf16x8 v; } b0, b1;
  #pragma unroll
  for (int i=0;i<4;++i) {                  // fused exp+pack: no p[16] live array
    b0.u[i] = cvt_pk_bf16(exp2_fast(sv[2*i]-m),   exp2_fast(sv[2*i+1]-m));
    b1.u[i] = cvt_pk_bf16(exp2_fast(sv[8+2*i]-m), exp2_fast(sv[8+2*i+1]-m));
  }
  oA = MFMA(A0lo, b0.v, oA, 0,0,0);
  oA = MFMA(A0hi, b1.v, oA, 0,0,0);
  oB = MFMA(A1lo, b0.v, oB, 0,0,0);
  oB = MFMA(A1hi, b1.v, oB, 0,0,0);
  lacc = MFMA(ones, b0.v, lacc, 0,0,0);
  lacc = MFMA(ones, b1.v, lacc, 0,0,0);
}

// ---------------- bf16 MFMA flash attention: 1-wave blocks, 16 q/wave, 8 waves/SIMD ----
__global__ __launch_bounds__(64, 8) void k_flash7(
    const short* __restrict__ Qbf, const short* __restrict__ Kbf,
    const short* __restrict__ Vf, short* __restrict__ opart,
    float* __restrict__ mlp)
{
  const int lane = threadIdx.x;
  const int g = lane >> 4, c = lane & 15;
  const int flat = blockIdx.x;
  const int p  = flat % 80;          // (sp,h) fastest -> XCD-local K/V slices
  const int qb = flat / 80;
  const int h  = p & 7;
  const int sp = p >> 3;
  const int q0 = qb * 16;
  const int qa = min(q0 + c, NQ-1);
  const bf16x8 qf = *(const bf16x8*)(Qbf + (size_t)qa*CDIM + h*DH + g*8);
  bf16x8 ones;
  #pragma unroll
  for (int i=0;i<8;++i) ones[i] = (short)0x3F80;
  const int kbase = sp*KPS;
  const size_t doff = (size_t)h*DH + g*8;
  const short* kbp = Kbf + (size_t)(kbase + c)*CDIM + doff;
  const short* vfp = Vf + (size_t)(sp*NH + h)*(TILES*2048) + lane*8;
  const f32x4 z = {0.f,0.f,0.f,0.f};
  f32x4 oA = z, oB = z, lacc = z;
  float mv = -INFINITY;

  bf16x8 kc0 = *(const bf16x8*)(kbp);
  bf16x8 kc1 = *(const bf16x8*)(kbp + (size_t)16*CDIM);
  bf16x8 kc2 = *(const bf16x8*)(kbp + (size_t)32*CDIM);
  bf16x8 kc3 = *(const bf16x8*)(kbp + (size_t)48*CDIM);

  #pragma unroll
  for (int t = 0; t < FULLT; ++t) {
    const int kt = t*64;
    const f32x4 s0 = MFMA(kc0, qf, z, 0,0,0);
    const f32x4 s1 = MFMA(kc1, qf, z, 0,0,0);
    const f32x4 s2 = MFMA(kc2, qf, z, 0,0,0);
    const f32x4 s3 = MFMA(kc3, qf, z, 0,0,0);
    if (t+1 < FULLT) {
      kc0 = *(const bf16x8*)(kbp + (size_t)(kt+64)*CDIM);
      kc1 = *(const bf16x8*)(kbp + (size_t)(kt+80)*CDIM);
      kc2 = *(const bf16x8*)(kbp + (size_t)(kt+96)*CDIM);
      kc3 = *(const bf16x8*)(kbp + (size_t)(kt+112)*CDIM);
    }
    const short* vt = vfp + (size_t)t*2048;
    const bf16x8 A0lo = *(const bf16x8*)(vt       );
    const bf16x8 A1lo = *(const bf16x8*)(vt +  512);
    const bf16x8 A0hi = *(const bf16x8*)(vt + 1024);
    const bf16x8 A1hi = *(const bf16x8*)(vt + 1536);
    softmax_pv(s0,s1,s2,s3, false, g, mv, lacc, oA, oB, A0lo, A0hi, A1lo, A1hi, ones);
  }
  { // tail: 52 valid keys; K addr clamped, scores masked, Vf tail pre-zeroed
    const int kt = FULLT*64;
    const int ka0 = min(kbase + kt +      c, NKV-1);
    const int ka1 = min(kbase + kt + 16 + c, NKV-1);
    const int ka2 = min(kbase + kt + 32 + c, NKV-1);
    const int ka3 = min(kbase + kt + 48 + c, NKV-1);
    const bf16x8 kf0 = *(const bf16x8*)(Kbf + (size_t)ka0*CDIM + doff);
    const bf16x8 kf1 = *(const bf16x8*)(Kbf + (size_t)ka1*CDIM + doff);
    const bf16x8 kf2 = *(const bf16x8*)(Kbf + (size_t)ka2*CDIM + doff);
    const bf16x8 kf3 = *(const bf16x8*)(Kbf + (size_t)ka3*CDIM + doff);
    const f32x4 s0 = MFMA(kf0, qf, z, 0,0,0);
    const f32x4 s1 = MFMA(kf1, qf, z, 0,0,0);
    const f32x4 s2 = MFMA(kf2, qf, z, 0,0,0);
    const f32x4 s3 = MFMA(kf3, qf, z, 0,0,0);
    const short* vt = vfp + (size_t)FULLT*2048;
    const bf16x8 A0lo = *(const bf16x8*)(vt       );
    const bf16x8 A1lo = *(const bf16x8*)(vt +  512);
    const bf16x8 A0hi = *(const bf16x8*)(vt + 1024);
    const bf16x8 A1hi = *(const bf16x8*)(vt + 1536);
    softmax_pv(s0,s1,s2,s3, true, g, mv, lacc, oA, oB, A0lo, A0hi, A1lo, A1hi, ones);
  }
  const size_t ob0 = (size_t)(sp*NH + h)*NQ;
  const int qw = q0 + c;
  if (qw < NQ) {
    const size_t b = (ob0 + qw)*DH;
    #pragma unroll
    for (int r=0;r<4;++r) {
      opart[b +      g*4 + r] = f2bf(oA[r]);
      opart[b + 16 + g*4 + r] = f2bf(oB[r]);
    }
    if (g == 0) { mlp[(ob0 + qw)*2] = mv; mlp[(ob0 + qw)*2+1] = lacc[0]; }
  }
}

// ---------------- row LayerNorm ----------------
__global__ __launch_bounds__(256) void k_ln(
    const float* __restrict__ x, const float* __restrict__ g,
    const float* __restrict__ b, const float* __restrict__ post_res,
    float* __restrict__ out)
{
  const int row = blockIdx.x, c = threadIdx.x;
  const size_t idx = (size_t)row*CDIM + c;
  const float v = x[idx];
  __shared__ float red[4];
  float s = v;
  #pragma unroll
  for (int m = 1; m < 64; m <<= 1) s += __shfl_xor(s, m);
  if ((c & 63) == 0) red[c >> 6] = s;
  __syncthreads();
  const float mean = (red[0]+red[1]+red[2]+red[3]) * (1.f/256.f);
  const float dv = v - mean;
  __syncthreads();
  float s2 = dv*dv;
  #pragma unroll
  for (int m = 1; m < 64; m <<= 1) s2 += __shfl_xor(s2, m);
  if ((c & 63) == 0) red[c >> 6] = s2;
  __syncthreads();
  const float var = (red[0]+red[1]+red[2]+red[3]) * (1.f/256.f);
  float o = dv * rsqrtf(var + 1e-5f) * g[c] + b[c];
  if (post_res) o += post_res[idx];
  out[idx] = o;
}

// ---------------- fused attn_w GEMV + softmax(24) + sampling + agg ----------------
__global__ __launch_bounds__(256) void k_sample_agg(
    const float* __restrict__ q1, const unsigned short* __restrict__ imgT,
    const float* __restrict__ l2i, const float* __restrict__ awW,
    const float* __restrict__ awb, float* __restrict__ agg)
{
  const int q = blockIdx.x, tid = threadIdx.x;
  __shared__ float qrow[256];
  __shared__ float wl[24];
  __shared__ float fwx[24], fwy[24];
  __shared__ int iv[24], ix[24], iy[24];
  qrow[tid] = q1[(size_t)q*CDIM + tid];
  __syncthreads();
  if (tid < 192) {
    const int e = tid >> 3, s2 = tid & 7;
    float acc = 0.f;
    for (int c = s2; c < 256; c += 8) acc += qrow[c]*awW[e*256 + c];
    acc += __shfl_xor(acc,1);
    acc += __shfl_xor(acc,2);
    acc += __shfl_xor(acc,4);
    if (s2 == 0) wl[e] = acc + awb[e];
  }
  if (tid < 24) {
    const int e = tid, n = e >> 2, z = e & 3;
    const int iyq = q / 50, jxq = q % 50;
    const float rx = (jxq + 0.5f)*(1.f/50.f);
    const float ry = (iyq + 0.5f)*(1.f/50.f);
    const float rz = (z + 0.5f)*0.25f;
    const float X = rx*102.4f - 51.2f;
    const float Y = ry*102.4f - 51.2f;
    const float Z = rz*8.f - 5.f;
    const float* L = l2i + n*16;
    const float cx = L[0]*X + L[1]*Y + L[2]*Z  + L[3];
    const float cy = L[4]*X + L[5]*Y + L[6]*Z  + L[7];
    const float cd = L[8]*X + L[9]*Y + L[10]*Z + L[11];
    const float dn = fmaxf(cd, 1e-5f);
    const float u = cx/dn, vv = cy/dn;
    const float gx = (u*(1.f/49.f) - 0.5f)*2.f;
    const float gy = (vv*(1.f/27.f) - 0.5f)*2.f;
    const int ok = (cd > 1e-5f) && (gx > -1.f) && (gx < 1.f) && (gy > -1.f) && (gy < 1.f);
    const float xf = ((gx + 1.f)*50.f - 1.f)*0.5f;
    const float yf = ((gy + 1.f)*28.f - 1.f)*0.5f;
    const float x0f = floorf(xf), y0f = floorf(yf);
    iv[e] = ok; ix[e] = (int)x0f; iy[e] = (int)y0f;
    fwx[e] = xf - x0f; fwy[e] = yf - y0f;
  }
  __syncthreads();
  float mx = -INFINITY;
  #pragma unroll
  for (int e = 0; e < 24; ++e) mx = fmaxf(mx, wl[e]);
  float se = 0.f;
  #pragma unroll
  for (int e = 0; e < 24; ++e) se += __expf(wl[e]-mx);
  const float inv = 1.f/se;
  const int c = tid;
  float acc = 0.f;
  #pragma unroll
  for (int e = 0; e < 24; ++e) {
    if (!iv[e]) continue;
    const float w = __expf(wl[e]-mx)*inv;
    const int n = e >> 2;
    const int x0 = ix[e], y0 = iy[e];
    const float wx = fwx[e], wy = fwy[e];
    const size_t base = (size_t)(n*28)*50;
    float v00 = (x0  >=0 && x0  <50 && y0  >=0 && y0  <28) ? bf2f(imgT[((base + (size_t)y0*50     + x0  ))*CDIM + c]) : 0.f;
    float v10 = (x0+1>=0 && x0+1<50 && y0  >=0 && y0  <28) ? bf2f(imgT[((base + (size_t)y0*50     + x0+1))*CDIM + c]) : 0.f;
    float v01 = (x0  >=0 && x0  <50 && y0+1>=0 && y0+1<28) ? bf2f(imgT[((base + (size_t)(y0+1)*50 + x0  ))*CDIM + c]) : 0.f;
    float v11 = (x0+1>=0 && x0+1<50 && y0+1>=0 && y0+1<28) ? bf2f(imgT[((base + (size_t)(y0+1)*50 + x0+1))*CDIM + c]) : 0.f;
    acc += w * ((v00*(1.f-wx) + v10*wx)*(1.f-wy) + (v01*(1.f-wx) + v11*wx)*wy);
  }
  agg[(size_t)q*CDIM + c] = acc;
}

// ---------------- launcher ----------------
extern "C" void kernel_launch(void* const* d_in, const int* in_sizes, int n_in,
                              void* d_out, int out_size, void* d_ws, size_t ws_size,
                              hipStream_t stream)
{
  const float* query = (const float*)d_in[0];
  const float* prev  = (const float*)d_in[1];
  const float* img   = (const float*)d_in[2];
  const float* ego   = (const float*)d_in[3];
  const float* l2i   = (const float*)d_in[4];
  const float* awW   = (const float*)d_in[5];
  const float* awb   = (const float*)d_in[6];
  const float* scab  = (const float*)d_in[8];
  const float* inb   = (const float*)d_in[10];
  const float* mob   = (const float*)d_in[12];
  const float* n1g   = (const float*)d_in[13];
  const float* n1b   = (const float*)d_in[14];
  const float* fb1   = (const float*)d_in[16];
  const float* fb2   = (const float*)d_in[18];
  const float* n2g   = (const float*)d_in[19];
  const float* n2b   = (const float*)d_in[20];
  float* out = (float*)d_out;
  float* ws  = (float*)d_ws;

  // ---- workspace layout (float offsets); total 7,865,472 f = 31.5 MB ----
  // phase A:
  float* kv    = ws;                        // [5000,256] f32   [0,        1280000)
  short* Qbf   = (short*)(ws + 1280000);    // [2500,256] bf16  [1280000,  1600000)
  short* Kbf   = (short*)(ws + 1600000);    // [5000,256] bf16  [1600000,  2240000)
  short* Vf    = (short*)(ws + 2240000);    // 1,310,720 bf16   [2240000,  2895360)
  short* opart = (short*)(ws + 2895360);    // [10,8,2500,32]   [2895360,  6095360)
  float* mlp   = ws + 6095360;              // [10,8,2500,2]    [6095360,  6495360)
  short* wf    = (short*)(ws + 6495360);    // 589,824 bf16     [6495360,  6790272)
  unsigned short* imgT = (unsigned short*)(ws + 6790272); // [6,28,50,256] [6790272, 7865472)
  // phase B reuse (disjoint per dispatch; Vf re-zeroed every call by k_prep):
  float* tmp1  = ws;                        // [0,       640000)  (kv dead)
  float* q1    = ws +  640000;              // [640000, 1280000)  (kv dead)
  float* aggb  = ws + 1280000;              // [1280000,1920000)  (Qbf dead, Kbf head dead)
  float* q2    = ws + 1920000;              // [1920000,2560000)  (Kbf dead)
  float* hbuf  = ws + 2560000;              // [2560000,3840000)  (Vf/opart-head dead)
  float* h2    = ws + 3840000;              // [3840000,4480000)  (opart dead)

  const float qscale = 0.2550727452794943f;  // (1/sqrt(32)) * log2(e)

  k_prep<<<8016, 256, 0, stream>>>(query, prev, ego, kv, img, imgT,
                                   (const float*)d_in[9], (const float*)d_in[11],
                                   (const float*)d_in[7], (const float*)d_in[15],
                                   (const float*)d_in[17], wf, (unsigned*)Vf);
  k_gemm_qkv<<<dim3(12,157), 256, 0, stream>>>(kv, wf, inb, Qbf, Kbf, Vf, qscale);
  k_flash7<<<158*80, 64, 0, stream>>>(Qbf, Kbf, Vf, opart, mlp);
  // moW GEMM with A = combine(opart, mlp) fused into staging; res = query
  k_gemm<<<dim3(4,79), 256, 0, stream>>>(nullptr, wf + 196608, mob, query, tmp1, nullptr,
                                         opart, mlp, NQ, 256, 256, 0, 0, 1, 1.0f);
  k_ln<<<NQ, 256, 0, stream>>>(tmp1, n1g, n1b, nullptr, q1);
  k_sample_agg<<<NQ, 256, 0, stream>>>(q1, imgT, l2i, awW, awb, aggb);
  k_gemm<<<dim3(4,79), 256, 0, stream>>>(aggb, wf + 262144, scab, q1, q2, nullptr,
                                         nullptr, nullptr, NQ, 256, 256, 0, 0, 0, 1.0f);
  k_gemm<<<dim3(8,79), 256, 0, stream>>>(q2, wf + 327680, fb1, nullptr, hbuf, nullptr,
                                         nullptr, nullptr, NQ, 512, 256, 1, 0, 0, 1.0f);
  k_gemm<<<dim3(4,79), 256, 0, stream>>>(hbuf, wf + 458752, fb2, nullptr, h2, nullptr,
                                         nullptr, nullptr, NQ, 256, 512, 0, 0, 0, 1.0f);
  k_ln<<<NQ, 256, 0, stream>>>(h2, n2g, n2b, q2, out);
}

// Round 13
// 140.989 us; speedup vs baseline: 1.3869x; 1.3869x over previous
//
#include <hip/hip_runtime.h>
#include <hip/hip_bf16.h>
#include <math.h>

#define NQ   2500
#define CDIM 256
#define NKV  5000
#define NH   8
#define DH   32
#define SPLITS 10
#define KPS   500          // keys per split
#define FULLT 7            // 7 full 64-key tiles
#define TILES 8            // 7 full + 1 tail
#define TAILNK 52          // 500 - 7*64

typedef __attribute__((ext_vector_type(8))) short bf16x8;
typedef __attribute__((ext_vector_type(4))) short short4v;
typedef __attribute__((ext_vector_type(4))) float f32x4;

#define MFMA __builtin_amdgcn_mfma_f32_16x16x32_bf16

__device__ __forceinline__ short f2bf(float f) {          // RNE
  union { float f; unsigned u; } v; v.f = f;
  unsigned r = v.u + 0x7FFFu + ((v.u >> 16) & 1u);
  return (short)(r >> 16);
}
__device__ __forceinline__ float bf2f(unsigned short s) {
  union { unsigned u; float f; } x; x.u = ((unsigned)s) << 16; return x.f;
}
__device__ __forceinline__ unsigned cvt_pk_bf16(float a, float b) { // [lo=a, hi=b] RNE
  unsigned r;
  asm("v_cvt_pk_bf16_f32 %0, %1, %2" : "=v"(r) : "v"(a), "v"(b));
  return r;
}
__device__ __forceinline__ float exp2_fast(float x) {
  float r; asm("v_exp_f32 %0, %1" : "=v"(r) : "v"(x)); return r;
}

// ============ fused prep: build_kv | transpose_img | prep_w (round-9 proven) ============
__global__ __launch_bounds__(256) void k_prep(
    const float* __restrict__ query, const float* __restrict__ prev,
    const float* __restrict__ ego, float* __restrict__ kv,
    const float* __restrict__ img, unsigned short* __restrict__ imgT,
    const float* __restrict__ inW, const float* __restrict__ moW,
    const float* __restrict__ scaW, const float* __restrict__ fW1,
    const float* __restrict__ fW2, short* __restrict__ wf)
{
  const int gid = blockIdx.x, tid = threadIdx.x;
  if (gid < NKV) {
    const int row = gid, c = tid;
    if (row < NQ) { kv[(size_t)row*CDIM + c] = query[(size_t)row*CDIM + c]; return; }
    int n = row - NQ;
    float txm = ego[3], tym = ego[7];
    float yaw = atan2f(ego[4], ego[0]);
    float cs = cosf(yaw), sn = sinf(yaw);
    float dx = txm * (1.f/51.2f), dy = tym * (1.f/51.2f);
    int i = n / 50, j = n % 50;
    float gx = (2.f*j + 1.f)*(1.f/50.f) - 1.f;
    float gy = (2.f*i + 1.f)*(1.f/50.f) - 1.f;
    float px = cs*gx - sn*gy + dx;
    float py = sn*gx + cs*gy + dy;
    float xf = ((px + 1.f)*50.f - 1.f)*0.5f;
    float yf = ((py + 1.f)*50.f - 1.f)*0.5f;
    float x0f = floorf(xf), y0f = floorf(yf);
    int x0 = (int)x0f, y0 = (int)y0f;
    float wx = xf - x0f, wy = yf - y0f;
    float v00 = (x0  >=0 && x0  <50 && y0  >=0 && y0  <50) ? prev[((size_t)(y0*50+x0      ))*CDIM + c] : 0.f;
    float v10 = (x0+1>=0 && x0+1<50 && y0  >=0 && y0  <50) ? prev[((size_t)(y0*50+x0+1    ))*CDIM + c] : 0.f;
    float v01 = (x0  >=0 && x0  <50 && y0+1>=0 && y0+1<50) ? prev[((size_t)((y0+1)*50+x0  ))*CDIM + c] : 0.f;
    float v11 = (x0+1>=0 && x0+1<50 && y0+1>=0 && y0+1<50) ? prev[((size_t)((y0+1)*50+x0+1))*CDIM + c] : 0.f;
    float v = (v00*(1.f-wx) + v10*wx)*(1.f-wy) + (v01*(1.f-wx) + v11*wx)*wy;
    kv[(size_t)row*CDIM + c] = v;
    return;
  }
  if (gid < NKV + 168) {
    const int b = gid - NKV;          // n*28 + y
    const int n = b / 28, y = b % 28;
    const int c = tid;
    for (int x = 0; x < 50; ++x)
      imgT[((size_t)((n*28 + y)*50 + x))*CDIM + c] =
        (unsigned short)f2bf(img[((size_t)(n*CDIM + c)*28 + y)*50 + x]);
    return;
  }
  {
    // weight fragments: wf[obase + ((n>>4)*(K/8) + (k>>3))*128 + (n&15)*8 + j]
    const int id = (gid - NKV - 168)*256 + tid;
    if (id >= 73728) return;
    const int s = id*8;
    const float* src; int off, K, obase;
    if      (s < 65536)  { src = inW;          off = s;          K = 256; obase = 0; }
    else if (s < 131072) { src = inW + 65536;  off = s - 65536;  K = 256; obase = 65536; }
    else if (s < 196608) { src = inW + 131072; off = s - 131072; K = 256; obase = 131072; }
    else if (s < 262144) { src = moW;          off = s - 196608; K = 256; obase = 196608; }
    else if (s < 327680) { src = scaW;         off = s - 262144; K = 256; obase = 262144; }
    else if (s < 458752) { src = fW1;          off = s - 327680; K = 256; obase = 327680; }
    else                 { src = fW2;          off = s - 458752; K = 512; obase = 458752; }
    const int n = off / K, k = off - n*K;
    short4v lo, hi;
    #pragma unroll
    for (int j = 0; j < 4; ++j) { lo[j] = f2bf(src[off+j]); hi[j] = f2bf(src[off+4+j]); }
    short* dst = wf + obase + (size_t)((n>>4)*(K>>3) + (k>>3))*128 + (n&15)*8;
    *(short4v*)dst = lo;
    *(short4v*)(dst+4) = hi;
  }
}

// ============ fused QKV GEMM (round-9 proven): -> Qbf / Kbf / VbfT[256][5000] ============
__global__ __launch_bounds__(256) void k_gemm_qkv(
    const float* __restrict__ A, const short* __restrict__ Wf,
    const float* __restrict__ bias, short* __restrict__ Qbf,
    short* __restrict__ Kbf, short* __restrict__ VbfT, float qscale)
{
  __shared__ short Abf[8][33][8];
  const int tid = threadIdx.x;
  const int lane = tid & 63, wid = tid >> 6;
  const int wm = wid >> 1, wn = wid & 1;
  const int g = lane >> 4, c = lane & 15;
  const int m0 = blockIdx.y << 5, n0 = blockIdx.x << 6;
  if (n0 < 256 && m0 >= NQ) return;    // block-uniform early out
  const int srow = tid >> 3, skq = tid & 7;
  const short* wfa = Wf + (size_t)((n0 + wn*32) >> 4)       * 32 * 128 + c*8;
  const short* wfb = Wf + (size_t)(((n0 + wn*32) >> 4) + 1) * 32 * 128 + c*8;
  f32x4 acc0 = {0.f,0.f,0.f,0.f}, acc1 = acc0;
  for (int k0 = 0; k0 < 256; k0 += 64) {
    const float* ap = A + (size_t)(m0+srow)*256 + k0 + skq*8;
    const float4 fa0 = *(const float4*)ap;
    const float4 fa1 = *(const float4*)(ap+4);
    __syncthreads();
    union { unsigned u[4]; bf16x8 v; } pa;
    pa.u[0] = cvt_pk_bf16(fa0.x, fa0.y);  pa.u[1] = cvt_pk_bf16(fa0.z, fa0.w);
    pa.u[2] = cvt_pk_bf16(fa1.x, fa1.y);  pa.u[3] = cvt_pk_bf16(fa1.z, fa1.w);
    *(bf16x8*)&Abf[skq][srow][0] = pa.v;
    __syncthreads();
    #pragma unroll
    for (int s = 0; s < 2; ++s) {
      const int kq = (k0 >> 3) + s*4 + g;
      const bf16x8 fA  = *(const bf16x8*)&Abf[s*4+g][wm*16 + c][0];
      const bf16x8 fW0 = *(const bf16x8*)(wfa + (size_t)kq*128);
      const bf16x8 fW1 = *(const bf16x8*)(wfb + (size_t)kq*128);
      acc0 = MFMA(fA, fW0, acc0, 0,0,0);
      acc1 = MFMA(fA, fW1, acc1, 0,0,0);
    }
  }
  const int nc0 = n0 + wn*32 + c, nc1 = nc0 + 16;
  const float b0v = bias[nc0], b1v = bias[nc1];
  #pragma unroll
  for (int r = 0; r < 4; ++r) {
    const int m = m0 + wm*16 + g*4 + r;
    if (m >= NKV) continue;
    const float v0 = acc0[r] + b0v;
    const float v1 = acc1[r] + b1v;
    if (nc0 < 256) {
      if (m < NQ) {
        Qbf[(size_t)m*256 + nc0] = f2bf(v0*qscale);
        Qbf[(size_t)m*256 + nc1] = f2bf(v1*qscale);
      }
    } else if (nc0 < 512) {
      Kbf[(size_t)m*256 + nc0 - 256] = f2bf(v0);
      Kbf[(size_t)m*256 + nc1 - 256] = f2bf(v1);
    } else {
      VbfT[(size_t)(nc0 - 512)*NKV + m] = f2bf(v0);
      VbfT[(size_t)(nc1 - 512)*NKV + m] = f2bf(v1);
    }
  }
}

// ---------------- VbfT [256][5000] -> Vf PV-fragments (round-9 proven) ----------------
__global__ __launch_bounds__(256) void k_repack_v(
    const short* __restrict__ VbfT, short* __restrict__ Vf)
{
  const int idx = blockIdx.x*256 + threadIdx.x;   // 5120 * 256 = 1,310,720 exact
  const int j    = idx & 7;
  const int lane = (idx >> 3) & 63;
  const int i    = (idx >> 9) & 1;
  const int kt2  = (idx >> 10) & 1;
  const int t    = (idx >> 11) & 7;
  const int h    = (idx >> 14) & 7;
  const int sp   = idx >> 17;
  const int gg = lane >> 4, cc = lane & 15;
  const int ko32 = ((j >> 2) << 4) | (gg << 2) | (j & 3);
  const int kin = t*64 + kt2*32 + ko32;
  const int d = i*16 + cc;
  short v = 0;
  if (kin < KPS) v = VbfT[(size_t)(h*32 + d)*NKV + sp*KPS + kin];
  Vf[idx] = v;
}

// ---------------- generic MFMA GEMM (frag-W); amode 1 = A from combine(opart,mlp) ----
// (round-11 proven verbatim)
__global__ __launch_bounds__(256) void k_gemm(
    const float* __restrict__ A, const short* __restrict__ Wf,
    const float* __restrict__ bias, const float* __restrict__ res,
    float* __restrict__ C, short* __restrict__ Cb,
    const short* __restrict__ opart, const float* __restrict__ mlp,
    int M, int N, int K, int relu, int mode, int amode, float scale)
{
  __shared__ short Abf[8][33][8];
  const int tid = threadIdx.x;
  const int lane = tid & 63, wid = tid >> 6;
  const int wm = wid >> 1, wn = wid & 1;
  const int g = lane >> 4, c = lane & 15;
  const int m0 = blockIdx.y << 5, n0 = blockIdx.x << 6;
  const int srow = tid >> 3, skq = tid & 7;
  const int kb8 = K >> 3;
  const short* wfa = Wf + (size_t)((n0 + wn*32) >> 4)       * kb8 * 128 + c*8;
  const short* wfb = Wf + (size_t)(((n0 + wn*32) >> 4) + 1) * kb8 * 128 + c*8;
  f32x4 acc0 = {0.f,0.f,0.f,0.f}, acc1 = acc0;
  const float4 z4 = make_float4(0.f,0.f,0.f,0.f);
  for (int k0 = 0; k0 < K; k0 += 64) {
    float4 fa0 = z4, fa1 = z4;
    const int mrow = m0 + srow;
    if (mrow < M) {
      if (amode == 0) {
        const float* ap = A + (size_t)mrow*K + k0 + skq*8;
        fa0 = *(const float4*)ap; fa1 = *(const float4*)(ap+4);
      } else {
        // A[mrow][c0..c0+7] = combine(opart, mlp) on the fly (exp2 domain)
        const int c0 = k0 + skq*8;
        const int hh = c0 >> 5, dd = c0 & 31;
        float mstar = -INFINITY;
        float ms[SPLITS], ls[SPLITS];
        #pragma unroll
        for (int s = 0; s < SPLITS; ++s) {
          const size_t b = (size_t)(s*NH + hh)*NQ + mrow;
          ms[s] = mlp[b*2]; ls[s] = mlp[b*2+1];
          mstar = fmaxf(mstar, ms[s]);
        }
        float num[8] = {0,0,0,0,0,0,0,0};
        float den = 0.f;
        #pragma unroll
        for (int s = 0; s < SPLITS; ++s) {
          const float e = exp2_fast(ms[s] - mstar);
          den += ls[s]*e;
          const size_t b = (size_t)(s*NH + hh)*NQ + mrow;
          const short* op = opart + b*DH + dd;
          #pragma unroll
          for (int j = 0; j < 8; ++j) num[j] += bf2f((unsigned short)op[j])*e;
        }
        const float inv = 1.f/den;
        fa0.x = num[0]*inv; fa0.y = num[1]*inv; fa0.z = num[2]*inv; fa0.w = num[3]*inv;
        fa1.x = num[4]*inv; fa1.y = num[5]*inv; fa1.z = num[6]*inv; fa1.w = num[7]*inv;
      }
    }
    __syncthreads();
    union { unsigned u[4]; bf16x8 v; } pa;
    pa.u[0] = cvt_pk_bf16(fa0.x, fa0.y);  pa.u[1] = cvt_pk_bf16(fa0.z, fa0.w);
    pa.u[2] = cvt_pk_bf16(fa1.x, fa1.y);  pa.u[3] = cvt_pk_bf16(fa1.z, fa1.w);
    *(bf16x8*)&Abf[skq][srow][0] = pa.v;
    __syncthreads();
    #pragma unroll
    for (int s = 0; s < 2; ++s) {
      const int kq = (k0 >> 3) + s*4 + g;
      const bf16x8 fA  = *(const bf16x8*)&Abf[s*4+g][wm*16 + c][0];
      const bf16x8 fW0 = *(const bf16x8*)(wfa + (size_t)kq*128);
      const bf16x8 fW1 = *(const bf16x8*)(wfb + (size_t)kq*128);
      acc0 = MFMA(fA, fW0, acc0, 0,0,0);
      acc1 = MFMA(fA, fW1, acc1, 0,0,0);
    }
  }
  const int nc0 = n0 + wn*32 + c, nc1 = nc0 + 16;
  const float b0v = bias[nc0], b1v = bias[nc1];
  #pragma unroll
  for (int r = 0; r < 4; ++r) {
    const int m = m0 + wm*16 + g*4 + r;
    if (m >= M) continue;
    float v0 = acc0[r] + b0v;
    float v1 = acc1[r] + b1v;
    if (mode == 0) {
      if (res) { v0 += res[(size_t)m*N + nc0]; v1 += res[(size_t)m*N + nc1]; }
      if (relu) { v0 = fmaxf(v0, 0.f); v1 = fmaxf(v1, 0.f); }
      C[(size_t)m*N + nc0] = v0;
      C[(size_t)m*N + nc1] = v1;
    } else {
      Cb[(size_t)m*N + nc0] = f2bf(v0*scale);
      Cb[(size_t)m*N + nc1] = f2bf(v1*scale);
    }
  }
}

// ---------------- flash softmax+PV (round-9 proven): defer-max, l via ones-MFMA ----------
__device__ __forceinline__ void softmax_pv(
    f32x4 s0, f32x4 s1, f32x4 s2, f32x4 s3, bool tail, int g,
    float& m, f32x4& lacc, f32x4& oA, f32x4& oB,
    bf16x8 A0lo, bf16x8 A0hi, bf16x8 A1lo, bf16x8 A1hi, bf16x8 ones)
{
  float sv[16];
  #pragma unroll
  for (int r=0;r<4;++r){ sv[r]=s0[r]; sv[4+r]=s1[r]; sv[8+r]=s2[r]; sv[12+r]=s3[r]; }
  if (tail) {
    #pragma unroll
    for (int i=0;i<16;++i) {
      const int kl = (i>>2)*16 + g*4 + (i&3);
      if (kl >= TAILNK) sv[i] = -1e30f;
    }
  }
  // max tree in 3-input groups (v_max3)
  const float t0 = fmaxf(fmaxf(sv[0], sv[1]), sv[2]);
  const float t1 = fmaxf(fmaxf(sv[3], sv[4]), sv[5]);
  const float t2 = fmaxf(fmaxf(sv[6], sv[7]), sv[8]);
  const float t3 = fmaxf(fmaxf(sv[9], sv[10]), sv[11]);
  const float t4 = fmaxf(fmaxf(sv[12], sv[13]), sv[14]);
  const float mx = fmaxf(fmaxf(fmaxf(t0, t1), t2), fmaxf(fmaxf(t3, t4), sv[15]));
  // T13: rescale only when running max must grow (wave-uniform branch)
  if (!__all(mx <= m + 8.f)) {
    float mm = fmaxf(mx, __shfl_xor(mx, 16));
    mm = fmaxf(mm, __shfl_xor(mm, 32));
    const float mn = fmaxf(m, mm);
    const float scl = exp2_fast(m - mn);   // first tile: exp2(-inf)=0
    m = mn;
    lacc[0] *= scl;                        // only [0] is ever read
    #pragma unroll
    for (int r=0;r<4;++r){ oA[r]*=scl; oB[r]*=scl; }
  }
  float p[16];
  #pragma unroll
  for (int i=0;i<16;++i) p[i] = exp2_fast(sv[i]-m);
  union { unsigned u[4]; bf16x8 v; } b0, b1;
  #pragma unroll
  for (int i=0;i<4;++i) {
    b0.u[i] = cvt_pk_bf16(p[2*i],   p[2*i+1]);
    b1.u[i] = cvt_pk_bf16(p[8+2*i], p[8+2*i+1]);
  }
  oA = MFMA(A0lo, b0.v, oA, 0,0,0);
  oA = MFMA(A0hi, b1.v, oA, 0,0,0);
  oB = MFMA(A1lo, b0.v, oB, 0,0,0);
  oB = MFMA(A1hi, b1.v, oB, 0,0,0);
  lacc = MFMA(ones, b0.v, lacc, 0,0,0);   // row-sums: l += sum_k p[k]
  lacc = MFMA(ones, b1.v, lacc, 0,0,0);
}

// ---------------- bf16 MFMA flash attention (round-9 proven): 1-wave, 32 q/wave ----
__global__ __launch_bounds__(64) void k_flash6(
    const short* __restrict__ Qbf, const short* __restrict__ Kbf,
    const short* __restrict__ Vf, short* __restrict__ opart,
    float* __restrict__ mlp)
{
  const int lane = threadIdx.x;
  const int g = lane >> 4, c = lane & 15;
  const int flat = blockIdx.x;
  const int p  = flat % 80;
  const int qb = flat / 80;
  const int h  = p & 7;
  const int sp = p >> 3;
  const int q0 = qb * 32;
  const int qa  = min(q0 +      c, NQ-1);
  const int qb2 = min(q0 + 16 + c, NQ-1);
  const bf16x8 qf0 = *(const bf16x8*)(Qbf + (size_t)qa *CDIM + h*DH + g*8);
  const bf16x8 qf1 = *(const bf16x8*)(Qbf + (size_t)qb2*CDIM + h*DH + g*8);
  bf16x8 ones;
  #pragma unroll
  for (int i=0;i<8;++i) ones[i] = (short)0x3F80;
  const int kbase = sp*KPS;
  const size_t doff = (size_t)h*DH + g*8;
  const short* kbp = Kbf + (size_t)(kbase + c)*CDIM + doff;
  const short* vfp = Vf + (size_t)(sp*NH + h)*(TILES*2048) + lane*8;
  const f32x4 z = {0.f,0.f,0.f,0.f};
  f32x4 o00 = z, o01 = z, o10 = z, o11 = z;
  f32x4 lacc0 = z, lacc1 = z;
  float m0v = -INFINITY, m1v = -INFINITY;

  bf16x8 kc0 = *(const bf16x8*)(kbp);
  bf16x8 kc1 = *(const bf16x8*)(kbp + (size_t)16*CDIM);
  bf16x8 kc2 = *(const bf16x8*)(kbp + (size_t)32*CDIM);
  bf16x8 kc3 = *(const bf16x8*)(kbp + (size_t)48*CDIM);

  #pragma unroll
  for (int t = 0; t < FULLT; ++t) {
    const int kt = t*64;
    const f32x4 s00 = MFMA(kc0, qf0, z, 0,0,0);
    const f32x4 s01 = MFMA(kc1, qf0, z, 0,0,0);
    const f32x4 s02 = MFMA(kc2, qf0, z, 0,0,0);
    const f32x4 s03 = MFMA(kc3, qf0, z, 0,0,0);
    const f32x4 s10 = MFMA(kc0, qf1, z, 0,0,0);
    const f32x4 s11 = MFMA(kc1, qf1, z, 0,0,0);
    const f32x4 s12 = MFMA(kc2, qf1, z, 0,0,0);
    const f32x4 s13 = MFMA(kc3, qf1, z, 0,0,0);
    if (t+1 < FULLT) {
      kc0 = *(const bf16x8*)(kbp + (size_t)(kt+64)*CDIM);
      kc1 = *(const bf16x8*)(kbp + (size_t)(kt+80)*CDIM);
      kc2 = *(const bf16x8*)(kbp + (size_t)(kt+96)*CDIM);
      kc3 = *(const bf16x8*)(kbp + (size_t)(kt+112)*CDIM);
    }
    const short* vt = vfp + (size_t)t*2048;
    const bf16x8 A0lo = *(const bf16x8*)(vt       );
    const bf16x8 A1lo = *(const bf16x8*)(vt +  512);
    const bf16x8 A0hi = *(const bf16x8*)(vt + 1024);
    const bf16x8 A1hi = *(const bf16x8*)(vt + 1536);
    softmax_pv(s00,s01,s02,s03, false, g, m0v, lacc0, o00, o01, A0lo, A0hi, A1lo, A1hi, ones);
    softmax_pv(s10,s11,s12,s13, false, g, m1v, lacc1, o10, o11, A0lo, A0hi, A1lo, A1hi, ones);
  }
  { // tail: 52 valid keys; K addr clamped, scores masked, Vf zero-filled by repack
    const int kt = FULLT*64;
    const int ka0 = min(kbase + kt +      c, NKV-1);
    const int ka1 = min(kbase + kt + 16 + c, NKV-1);
    const int ka2 = min(kbase + kt + 32 + c, NKV-1);
    const int ka3 = min(kbase + kt + 48 + c, NKV-1);
    const bf16x8 kf0 = *(const bf16x8*)(Kbf + (size_t)ka0*CDIM + doff);
    const bf16x8 kf1 = *(const bf16x8*)(Kbf + (size_t)ka1*CDIM + doff);
    const bf16x8 kf2 = *(const bf16x8*)(Kbf + (size_t)ka2*CDIM + doff);
    const bf16x8 kf3 = *(const bf16x8*)(Kbf + (size_t)ka3*CDIM + doff);
    const f32x4 s00 = MFMA(kf0, qf0, z, 0,0,0);
    const f32x4 s01 = MFMA(kf1, qf0, z, 0,0,0);
    const f32x4 s02 = MFMA(kf2, qf0, z, 0,0,0);
    const f32x4 s03 = MFMA(kf3, qf0, z, 0,0,0);
    const f32x4 s10 = MFMA(kf0, qf1, z, 0,0,0);
    const f32x4 s11 = MFMA(kf1, qf1, z, 0,0,0);
    const f32x4 s12 = MFMA(kf2, qf1, z, 0,0,0);
    const f32x4 s13 = MFMA(kf3, qf1, z, 0,0,0);
    const short* vt = vfp + (size_t)FULLT*2048;
    const bf16x8 A0lo = *(const bf16x8*)(vt       );
    const bf16x8 A1lo = *(const bf16x8*)(vt +  512);
    const bf16x8 A0hi = *(const bf16x8*)(vt + 1024);
    const bf16x8 A1hi = *(const bf16x8*)(vt + 1536);
    softmax_pv(s00,s01,s02,s03, true, g, m0v, lacc0, o00, o01, A0lo, A0hi, A1lo, A1hi, ones);
    softmax_pv(s10,s11,s12,s13, true, g, m1v, lacc1, o10, o11, A0lo, A0hi, A1lo, A1hi, ones);
  }
  const size_t ob0 = (size_t)(sp*NH + h)*NQ;
  const int qw0 = q0 + c;
  if (qw0 < NQ) {
    const size_t b = (ob0 + qw0)*DH;
    #pragma unroll
    for (int r=0;r<4;++r) {
      opart[b +      g*4 + r] = f2bf(o00[r]);
      opart[b + 16 + g*4 + r] = f2bf(o01[r]);
    }
    if (g == 0) { mlp[(ob0 + qw0)*2] = m0v; mlp[(ob0 + qw0)*2+1] = lacc0[0]; }
  }
  const int qw1 = q0 + 16 + c;
  if (qw1 < NQ) {
    const size_t b = (ob0 + qw1)*DH;
    #pragma unroll
    for (int r=0;r<4;++r) {
      opart[b +      g*4 + r] = f2bf(o10[r]);
      opart[b + 16 + g*4 + r] = f2bf(o11[r]);
    }
    if (g == 0) { mlp[(ob0 + qw1)*2] = m1v; mlp[(ob0 + qw1)*2+1] = lacc1[0]; }
  }
}

// ---------------- row LayerNorm ----------------
__global__ __launch_bounds__(256) void k_ln(
    const float* __restrict__ x, const float* __restrict__ g,
    const float* __restrict__ b, const float* __restrict__ post_res,
    float* __restrict__ out)
{
  const int row = blockIdx.x, c = threadIdx.x;
  const size_t idx = (size_t)row*CDIM + c;
  const float v = x[idx];
  __shared__ float red[4];
  float s = v;
  #pragma unroll
  for (int m = 1; m < 64; m <<= 1) s += __shfl_xor(s, m);
  if ((c & 63) == 0) red[c >> 6] = s;
  __syncthreads();
  const float mean = (red[0]+red[1]+red[2]+red[3]) * (1.f/256.f);
  const float dv = v - mean;
  __syncthreads();
  float s2 = dv*dv;
  #pragma unroll
  for (int m = 1; m < 64; m <<= 1) s2 += __shfl_xor(s2, m);
  if ((c & 63) == 0) red[c >> 6] = s2;
  __syncthreads();
  const float var = (red[0]+red[1]+red[2]+red[3]) * (1.f/256.f);
  float o = dv * rsqrtf(var + 1e-5f) * g[c] + b[c];
  if (post_res) o += post_res[idx];
  out[idx] = o;
}

// ---------------- fused attn_w GEMV + softmax(24) + sampling + agg ----------------
__global__ __launch_bounds__(256) void k_sample_agg(
    const float* __restrict__ q1, const unsigned short* __restrict__ imgT,
    const float* __restrict__ l2i, const float* __restrict__ awW,
    const float* __restrict__ awb, float* __restrict__ agg)
{
  const int q = blockIdx.x, tid = threadIdx.x;
  __shared__ float qrow[256];
  __shared__ float wl[24];
  __shared__ float fwx[24], fwy[24];
  __shared__ int iv[24], ix[24], iy[24];
  qrow[tid] = q1[(size_t)q*CDIM + tid];
  __syncthreads();
  if (tid < 192) {
    const int e = tid >> 3, s2 = tid & 7;
    float acc = 0.f;
    for (int c = s2; c < 256; c += 8) acc += qrow[c]*awW[e*256 + c];
    acc += __shfl_xor(acc,1);
    acc += __shfl_xor(acc,2);
    acc += __shfl_xor(acc,4);
    if (s2 == 0) wl[e] = acc + awb[e];
  }
  if (tid < 24) {
    const int e = tid, n = e >> 2, z = e & 3;
    const int iyq = q / 50, jxq = q % 50;
    const float rx = (jxq + 0.5f)*(1.f/50.f);
    const float ry = (iyq + 0.5f)*(1.f/50.f);
    const float rz = (z + 0.5f)*0.25f;
    const float X = rx*102.4f - 51.2f;
    const float Y = ry*102.4f - 51.2f;
    const float Z = rz*8.f - 5.f;
    const float* L = l2i + n*16;
    const float cx = L[0]*X + L[1]*Y + L[2]*Z  + L[3];
    const float cy = L[4]*X + L[5]*Y + L[6]*Z  + L[7];
    const float cd = L[8]*X + L[9]*Y + L[10]*Z + L[11];
    const float dn = fmaxf(cd, 1e-5f);
    const float u = cx/dn, vv = cy/dn;
    const float gx = (u*(1.f/49.f) - 0.5f)*2.f;
    const float gy = (vv*(1.f/27.f) - 0.5f)*2.f;
    const int ok = (cd > 1e-5f) && (gx > -1.f) && (gx < 1.f) && (gy > -1.f) && (gy < 1.f);
    const float xf = ((gx + 1.f)*50.f - 1.f)*0.5f;
    const float yf = ((gy + 1.f)*28.f - 1.f)*0.5f;
    const float x0f = floorf(xf), y0f = floorf(yf);
    iv[e] = ok; ix[e] = (int)x0f; iy[e] = (int)y0f;
    fwx[e] = xf - x0f; fwy[e] = yf - y0f;
  }
  __syncthreads();
  float mx = -INFINITY;
  #pragma unroll
  for (int e = 0; e < 24; ++e) mx = fmaxf(mx, wl[e]);
  float se = 0.f;
  #pragma unroll
  for (int e = 0; e < 24; ++e) se += __expf(wl[e]-mx);
  const float inv = 1.f/se;
  const int c = tid;
  float acc = 0.f;
  #pragma unroll
  for (int e = 0; e < 24; ++e) {
    if (!iv[e]) continue;
    const float w = __expf(wl[e]-mx)*inv;
    const int n = e >> 2;
    const int x0 = ix[e], y0 = iy[e];
    const float wx = fwx[e], wy = fwy[e];
    const size_t base = (size_t)(n*28)*50;
    float v00 = (x0  >=0 && x0  <50 && y0  >=0 && y0  <28) ? bf2f(imgT[((base + (size_t)y0*50     + x0  ))*CDIM + c]) : 0.f;
    float v10 = (x0+1>=0 && x0+1<50 && y0  >=0 && y0  <28) ? bf2f(imgT[((base + (size_t)y0*50     + x0+1))*CDIM + c]) : 0.f;
    float v01 = (x0  >=0 && x0  <50 && y0+1>=0 && y0+1<28) ? bf2f(imgT[((base + (size_t)(y0+1)*50 + x0  ))*CDIM + c]) : 0.f;
    float v11 = (x0+1>=0 && x0+1<50 && y0+1>=0 && y0+1<28) ? bf2f(imgT[((base + (size_t)(y0+1)*50 + x0+1))*CDIM + c]) : 0.f;
    acc += w * ((v00*(1.f-wx) + v10*wx)*(1.f-wy) + (v01*(1.f-wx) + v11*wx)*wy);
  }
  agg[(size_t)q*CDIM + c] = acc;
}

// ---------------- launcher ----------------
extern "C" void kernel_launch(void* const* d_in, const int* in_sizes, int n_in,
                              void* d_out, int out_size, void* d_ws, size_t ws_size,
                              hipStream_t stream)
{
  const float* query = (const float*)d_in[0];
  const float* prev  = (const float*)d_in[1];
  const float* img   = (const float*)d_in[2];
  const float* ego   = (const float*)d_in[3];
  const float* l2i   = (const float*)d_in[4];
  const float* awW   = (const float*)d_in[5];
  const float* awb   = (const float*)d_in[6];
  const float* scab  = (const float*)d_in[8];
  const float* inb   = (const float*)d_in[10];
  const float* mob   = (const float*)d_in[12];
  const float* n1g   = (const float*)d_in[13];
  const float* n1b   = (const float*)d_in[14];
  const float* fb1   = (const float*)d_in[16];
  const float* fb2   = (const float*)d_in[18];
  const float* n2g   = (const float*)d_in[19];
  const float* n2b   = (const float*)d_in[20];
  float* out = (float*)d_out;
  float* ws  = (float*)d_ws;

  // ---- workspace layout (float offsets, round-9 proven); total 8,505,472 f = 34.0 MB ----
  float* kv    = ws;                        // [5000,256] f32   [0,        1280000)
  short* Qbf   = (short*)(ws + 1280000);    // [2500,256] bf16  [1280000,  1600000)
  short* Kbf   = (short*)(ws + 1600000);    // [5000,256] bf16  [1600000,  2240000)
  short* VbfT  = (short*)(ws + 2240000);    // [256,5000] bf16  [2240000,  2880000)
  short* Vf    = (short*)(ws + 2880000);    // 1,310,720 bf16   [2880000,  3535360)
  short* opart = (short*)(ws + 3535360);    // [10,8,2500,32]   [3535360,  6735360)
  float* mlp   = ws + 6735360;              // [10,8,2500,2]    [6735360,  7135360)
  short* wf    = (short*)(ws + 7135360);    // 589,824 bf16     [7135360,  7430272)
  unsigned short* imgT = (unsigned short*)(ws + 7430272); // [6,28,50,256] [7430272, 8505472)
  // phase B reuse (disjoint per dispatch; opart/mlp live until moW GEMM):
  float* tmp1  = ws;                        // [0,       640000)  (kv dead)
  float* q1    = ws +  640000;              // [640000, 1280000)  (kv dead)
  float* aggb  = ws + 1280000;              // [1280000,1920000)  (Qbf/Kbf-head dead)
  float* q2    = ws + 1920000;              // [1920000,2560000)  (Kbf-tail/VbfT-head dead)
  float* hbuf  = ws + 2560000;              // [2560000,3840000)  (VbfT/Vf/opart-head dead)
  float* h2    = ws + 3840000;              // [3840000,4480000)  (opart dead)

  const float qscale = 0.2550727452794943f;  // (1/sqrt(32)) * log2(e)

  k_prep<<<5456, 256, 0, stream>>>(query, prev, ego, kv, img, imgT,
                                   (const float*)d_in[9], (const float*)d_in[11],
                                   (const float*)d_in[7], (const float*)d_in[15],
                                   (const float*)d_in[17], wf);
  k_gemm_qkv<<<dim3(12,157), 256, 0, stream>>>(kv, wf, inb, Qbf, Kbf, VbfT, qscale);
  k_repack_v<<<5120, 256, 0, stream>>>(VbfT, Vf);
  k_flash6<<<79*80, 64, 0, stream>>>(Qbf, Kbf, Vf, opart, mlp);
  // moW GEMM with A = combine(opart, mlp) fused into staging; res = query
  k_gemm<<<dim3(4,79), 256, 0, stream>>>(nullptr, wf + 196608, mob, query, tmp1, nullptr,
                                         opart, mlp, NQ, 256, 256, 0, 0, 1, 1.0f);
  k_ln<<<NQ, 256, 0, stream>>>(tmp1, n1g, n1b, nullptr, q1);
  k_sample_agg<<<NQ, 256, 0, stream>>>(q1, imgT, l2i, awW, awb, aggb);
  k_gemm<<<dim3(4,79), 256, 0, stream>>>(aggb, wf + 262144, scab, q1, q2, nullptr,
                                         nullptr, nullptr, NQ, 256, 256, 0, 0, 0, 1.0f);
  k_gemm<<<dim3(8,79), 256, 0, stream>>>(q2, wf + 327680, fb1, nullptr, hbuf, nullptr,
                                         nullptr, nullptr, NQ, 512, 256, 1, 0, 0, 1.0f);
  k_gemm<<<dim3(4,79), 256, 0, stream>>>(hbuf, wf + 458752, fb2, nullptr, h2, nullptr,
                                         nullptr, nullptr, NQ, 256, 512, 0, 0, 0, 1.0f);
  k_ln<<<NQ, 256, 0, stream>>>(h2, n2g, n2b, q2, out);
}

// Round 15
// 140.810 us; speedup vs baseline: 1.3886x; 1.0013x over previous
//
#include <hip/hip_runtime.h>
#include <hip/hip_bf16.h>
#include <math.h>

#define NQ   2500
#define CDIM 256
#define NKV  5000
#define NH   8
#define DH   32
#define SPLITS 10
#define KPS   500          // keys per split
#define FULLT 7            // 7 full 64-key tiles
#define TILES 8            // 7 full + 1 tail
#define TAILNK 52          // 500 - 7*64

typedef __attribute__((ext_vector_type(8))) short bf16x8;
typedef __attribute__((ext_vector_type(4))) short short4v;
typedef __attribute__((ext_vector_type(4))) float f32x4;

#define MFMA __builtin_amdgcn_mfma_f32_16x16x32_bf16

__device__ __forceinline__ short f2bf(float f) {          // RNE
  union { float f; unsigned u; } v; v.f = f;
  unsigned r = v.u + 0x7FFFu + ((v.u >> 16) & 1u);
  return (short)(r >> 16);
}
__device__ __forceinline__ float bf2f(unsigned short s) {
  union { unsigned u; float f; } x; x.u = ((unsigned)s) << 16; return x.f;
}
__device__ __forceinline__ unsigned cvt_pk_bf16(float a, float b) { // [lo=a, hi=b] RNE
  unsigned r;
  asm("v_cvt_pk_bf16_f32 %0, %1, %2" : "=v"(r) : "v"(a), "v"(b));
  return r;
}
__device__ __forceinline__ float exp2_fast(float x) {
  float r; asm("v_exp_f32 %0, %1" : "=v"(r) : "v"(x)); return r;
}

// ============ fused prep: build_kv | transpose_img | prep_w (round-9 proven) ============
__global__ __launch_bounds__(256) void k_prep(
    const float* __restrict__ query, const float* __restrict__ prev,
    const float* __restrict__ ego, float* __restrict__ kv,
    const float* __restrict__ img, unsigned short* __restrict__ imgT,
    const float* __restrict__ inW, const float* __restrict__ moW,
    const float* __restrict__ scaW, const float* __restrict__ fW1,
    const float* __restrict__ fW2, short* __restrict__ wf)
{
  const int gid = blockIdx.x, tid = threadIdx.x;
  if (gid < NKV) {
    const int row = gid, c = tid;
    if (row < NQ) { kv[(size_t)row*CDIM + c] = query[(size_t)row*CDIM + c]; return; }
    int n = row - NQ;
    float txm = ego[3], tym = ego[7];
    float yaw = atan2f(ego[4], ego[0]);
    float cs = cosf(yaw), sn = sinf(yaw);
    float dx = txm * (1.f/51.2f), dy = tym * (1.f/51.2f);
    int i = n / 50, j = n % 50;
    float gx = (2.f*j + 1.f)*(1.f/50.f) - 1.f;
    float gy = (2.f*i + 1.f)*(1.f/50.f) - 1.f;
    float px = cs*gx - sn*gy + dx;
    float py = sn*gx + cs*gy + dy;
    float xf = ((px + 1.f)*50.f - 1.f)*0.5f;
    float yf = ((py + 1.f)*50.f - 1.f)*0.5f;
    float x0f = floorf(xf), y0f = floorf(yf);
    int x0 = (int)x0f, y0 = (int)y0f;
    float wx = xf - x0f, wy = yf - y0f;
    float v00 = (x0  >=0 && x0  <50 && y0  >=0 && y0  <50) ? prev[((size_t)(y0*50+x0      ))*CDIM + c] : 0.f;
    float v10 = (x0+1>=0 && x0+1<50 && y0  >=0 && y0  <50) ? prev[((size_t)(y0*50+x0+1    ))*CDIM + c] : 0.f;
    float v01 = (x0  >=0 && x0  <50 && y0+1>=0 && y0+1<50) ? prev[((size_t)((y0+1)*50+x0  ))*CDIM + c] : 0.f;
    float v11 = (x0+1>=0 && x0+1<50 && y0+1>=0 && y0+1<50) ? prev[((size_t)((y0+1)*50+x0+1))*CDIM + c] : 0.f;
    float v = (v00*(1.f-wx) + v10*wx)*(1.f-wy) + (v01*(1.f-wx) + v11*wx)*wy;
    kv[(size_t)row*CDIM + c] = v;
    return;
  }
  if (gid < NKV + 168) {
    const int b = gid - NKV;          // n*28 + y
    const int n = b / 28, y = b % 28;
    const int c = tid;
    for (int x = 0; x < 50; ++x)
      imgT[((size_t)((n*28 + y)*50 + x))*CDIM + c] =
        (unsigned short)f2bf(img[((size_t)(n*CDIM + c)*28 + y)*50 + x]);
    return;
  }
  {
    // weight fragments: wf[obase + ((n>>4)*(K/8) + (k>>3))*128 + (n&15)*8 + j]
    const int id = (gid - NKV - 168)*256 + tid;
    if (id >= 73728) return;
    const int s = id*8;
    const float* src; int off, K, obase;
    if      (s < 65536)  { src = inW;          off = s;          K = 256; obase = 0; }
    else if (s < 131072) { src = inW + 65536;  off = s - 65536;  K = 256; obase = 65536; }
    else if (s < 196608) { src = inW + 131072; off = s - 131072; K = 256; obase = 131072; }
    else if (s < 262144) { src = moW;          off = s - 196608; K = 256; obase = 196608; }
    else if (s < 327680) { src = scaW;         off = s - 262144; K = 256; obase = 262144; }
    else if (s < 458752) { src = fW1;          off = s - 327680; K = 256; obase = 327680; }
    else                 { src = fW2;          off = s - 458752; K = 512; obase = 458752; }
    const int n = off / K, k = off - n*K;
    short4v lo, hi;
    #pragma unroll
    for (int j = 0; j < 4; ++j) { lo[j] = f2bf(src[off+j]); hi[j] = f2bf(src[off+4+j]); }
    short* dst = wf + obase + (size_t)((n>>4)*(K>>3) + (k>>3))*128 + (n&15)*8;
    *(short4v*)dst = lo;
    *(short4v*)(dst+4) = hi;
  }
}

// ============ fused QKV GEMM (round-9 proven): -> Qbf / Kbf / VbfT[256][5000] ============
__global__ __launch_bounds__(256) void k_gemm_qkv(
    const float* __restrict__ A, const short* __restrict__ Wf,
    const float* __restrict__ bias, short* __restrict__ Qbf,
    short* __restrict__ Kbf, short* __restrict__ VbfT, float qscale)
{
  __shared__ short Abf[8][33][8];
  const int tid = threadIdx.x;
  const int lane = tid & 63, wid = tid >> 6;
  const int wm = wid >> 1, wn = wid & 1;
  const int g = lane >> 4, c = lane & 15;
  const int m0 = blockIdx.y << 5, n0 = blockIdx.x << 6;
  if (n0 < 256 && m0 >= NQ) return;    // block-uniform early out
  const int srow = tid >> 3, skq = tid & 7;
  const short* wfa = Wf + (size_t)((n0 + wn*32) >> 4)       * 32 * 128 + c*8;
  const short* wfb = Wf + (size_t)(((n0 + wn*32) >> 4) + 1) * 32 * 128 + c*8;
  f32x4 acc0 = {0.f,0.f,0.f,0.f}, acc1 = acc0;
  for (int k0 = 0; k0 < 256; k0 += 64) {
    const float* ap = A + (size_t)(m0+srow)*256 + k0 + skq*8;
    const float4 fa0 = *(const float4*)ap;
    const float4 fa1 = *(const float4*)(ap+4);
    __syncthreads();
    union { unsigned u[4]; bf16x8 v; } pa;
    pa.u[0] = cvt_pk_bf16(fa0.x, fa0.y);  pa.u[1] = cvt_pk_bf16(fa0.z, fa0.w);
    pa.u[2] = cvt_pk_bf16(fa1.x, fa1.y);  pa.u[3] = cvt_pk_bf16(fa1.z, fa1.w);
    *(bf16x8*)&Abf[skq][srow][0] = pa.v;
    __syncthreads();
    #pragma unroll
    for (int s = 0; s < 2; ++s) {
      const int kq = (k0 >> 3) + s*4 + g;
      const bf16x8 fA  = *(const bf16x8*)&Abf[s*4+g][wm*16 + c][0];
      const bf16x8 fW0 = *(const bf16x8*)(wfa + (size_t)kq*128);
      const bf16x8 fW1 = *(const bf16x8*)(wfb + (size_t)kq*128);
      acc0 = MFMA(fA, fW0, acc0, 0,0,0);
      acc1 = MFMA(fA, fW1, acc1, 0,0,0);
    }
  }
  const int nc0 = n0 + wn*32 + c, nc1 = nc0 + 16;
  const float b0v = bias[nc0], b1v = bias[nc1];
  #pragma unroll
  for (int r = 0; r < 4; ++r) {
    const int m = m0 + wm*16 + g*4 + r;
    if (m >= NKV) continue;
    const float v0 = acc0[r] + b0v;
    const float v1 = acc1[r] + b1v;
    if (nc0 < 256) {
      if (m < NQ) {
        Qbf[(size_t)m*256 + nc0] = f2bf(v0*qscale);
        Qbf[(size_t)m*256 + nc1] = f2bf(v1*qscale);
      }
    } else if (nc0 < 512) {
      Kbf[(size_t)m*256 + nc0 - 256] = f2bf(v0);
      Kbf[(size_t)m*256 + nc1 - 256] = f2bf(v1);
    } else {
      VbfT[(size_t)(nc0 - 512)*NKV + m] = f2bf(v0);
      VbfT[(size_t)(nc1 - 512)*NKV + m] = f2bf(v1);
    }
  }
}

// ---------------- VbfT [256][5000] -> Vf PV-fragments (round-9 proven) ----------------
__global__ __launch_bounds__(256) void k_repack_v(
    const short* __restrict__ VbfT, short* __restrict__ Vf)
{
  const int idx = blockIdx.x*256 + threadIdx.x;   // 5120 * 256 = 1,310,720 exact
  const int j    = idx & 7;
  const int lane = (idx >> 3) & 63;
  const int i    = (idx >> 9) & 1;
  const int kt2  = (idx >> 10) & 1;
  const int t    = (idx >> 11) & 7;
  const int h    = (idx >> 14) & 7;
  const int sp   = idx >> 17;
  const int gg = lane >> 4, cc = lane & 15;
  const int ko32 = ((j >> 2) << 4) | (gg << 2) | (j & 3);
  const int kin = t*64 + kt2*32 + ko32;
  const int d = i*16 + cc;
  short v = 0;
  if (kin < KPS) v = VbfT[(size_t)(h*32 + d)*NKV + sp*KPS + kin];
  Vf[idx] = v;
}

// ---------------- generic MFMA GEMM (frag-W); amode 1 = A from combine(opart,mlp) ----
// (round-11/13 proven verbatim)
__global__ __launch_bounds__(256) void k_gemm(
    const float* __restrict__ A, const short* __restrict__ Wf,
    const float* __restrict__ bias, const float* __restrict__ res,
    float* __restrict__ C, short* __restrict__ Cb,
    const short* __restrict__ opart, const float* __restrict__ mlp,
    int M, int N, int K, int relu, int mode, int amode, float scale)
{
  __shared__ short Abf[8][33][8];
  const int tid = threadIdx.x;
  const int lane = tid & 63, wid = tid >> 6;
  const int wm = wid >> 1, wn = wid & 1;
  const int g = lane >> 4, c = lane & 15;
  const int m0 = blockIdx.y << 5, n0 = blockIdx.x << 6;
  const int srow = tid >> 3, skq = tid & 7;
  const int kb8 = K >> 3;
  const short* wfa = Wf + (size_t)((n0 + wn*32) >> 4)       * kb8 * 128 + c*8;
  const short* wfb = Wf + (size_t)(((n0 + wn*32) >> 4) + 1) * kb8 * 128 + c*8;
  f32x4 acc0 = {0.f,0.f,0.f,0.f}, acc1 = acc0;
  const float4 z4 = make_float4(0.f,0.f,0.f,0.f);
  for (int k0 = 0; k0 < K; k0 += 64) {
    float4 fa0 = z4, fa1 = z4;
    const int mrow = m0 + srow;
    if (mrow < M) {
      if (amode == 0) {
        const float* ap = A + (size_t)mrow*K + k0 + skq*8;
        fa0 = *(const float4*)ap; fa1 = *(const float4*)(ap+4);
      } else {
        // A[mrow][c0..c0+7] = combine(opart, mlp) on the fly (exp2 domain)
        const int c0 = k0 + skq*8;
        const int hh = c0 >> 5, dd = c0 & 31;
        float mstar = -INFINITY;
        float ms[SPLITS], ls[SPLITS];
        #pragma unroll
        for (int s = 0; s < SPLITS; ++s) {
          const size_t b = (size_t)(s*NH + hh)*NQ + mrow;
          ms[s] = mlp[b*2]; ls[s] = mlp[b*2+1];
          mstar = fmaxf(mstar, ms[s]);
        }
        float num[8] = {0,0,0,0,0,0,0,0};
        float den = 0.f;
        #pragma unroll
        for (int s = 0; s < SPLITS; ++s) {
          const float e = exp2_fast(ms[s] - mstar);
          den += ls[s]*e;
          const size_t b = (size_t)(s*NH + hh)*NQ + mrow;
          const short* op = opart + b*DH + dd;
          #pragma unroll
          for (int j = 0; j < 8; ++j) num[j] += bf2f((unsigned short)op[j])*e;
        }
        const float inv = 1.f/den;
        fa0.x = num[0]*inv; fa0.y = num[1]*inv; fa0.z = num[2]*inv; fa0.w = num[3]*inv;
        fa1.x = num[4]*inv; fa1.y = num[5]*inv; fa1.z = num[6]*inv; fa1.w = num[7]*inv;
      }
    }
    __syncthreads();
    union { unsigned u[4]; bf16x8 v; } pa;
    pa.u[0] = cvt_pk_bf16(fa0.x, fa0.y);  pa.u[1] = cvt_pk_bf16(fa0.z, fa0.w);
    pa.u[2] = cvt_pk_bf16(fa1.x, fa1.y);  pa.u[3] = cvt_pk_bf16(fa1.z, fa1.w);
    *(bf16x8*)&Abf[skq][srow][0] = pa.v;
    __syncthreads();
    #pragma unroll
    for (int s = 0; s < 2; ++s) {
      const int kq = (k0 >> 3) + s*4 + g;
      const bf16x8 fA  = *(const bf16x8*)&Abf[s*4+g][wm*16 + c][0];
      const bf16x8 fW0 = *(const bf16x8*)(wfa + (size_t)kq*128);
      const bf16x8 fW1 = *(const bf16x8*)(wfb + (size_t)kq*128);
      acc0 = MFMA(fA, fW0, acc0, 0,0,0);
      acc1 = MFMA(fA, fW1, acc1, 0,0,0);
    }
  }
  const int nc0 = n0 + wn*32 + c, nc1 = nc0 + 16;
  const float b0v = bias[nc0], b1v = bias[nc1];
  #pragma unroll
  for (int r = 0; r < 4; ++r) {
    const int m = m0 + wm*16 + g*4 + r;
    if (m >= M) continue;
    float v0 = acc0[r] + b0v;
    float v1 = acc1[r] + b1v;
    if (mode == 0) {
      if (res) { v0 += res[(size_t)m*N + nc0]; v1 += res[(size_t)m*N + nc1]; }
      if (relu) { v0 = fmaxf(v0, 0.f); v1 = fmaxf(v1, 0.f); }
      C[(size_t)m*N + nc0] = v0;
      C[(size_t)m*N + nc1] = v1;
    } else {
      Cb[(size_t)m*N + nc0] = f2bf(v0*scale);
      Cb[(size_t)m*N + nc1] = f2bf(v1*scale);
    }
  }
}

// ---------------- flash softmax+PV (round-9 proven): defer-max, l via ones-MFMA ----------
__device__ __forceinline__ void softmax_pv(
    f32x4 s0, f32x4 s1, f32x4 s2, f32x4 s3, bool tail, int g,
    float& m, f32x4& lacc, f32x4& oA, f32x4& oB,
    bf16x8 A0lo, bf16x8 A0hi, bf16x8 A1lo, bf16x8 A1hi, bf16x8 ones)
{
  float sv[16];
  #pragma unroll
  for (int r=0;r<4;++r){ sv[r]=s0[r]; sv[4+r]=s1[r]; sv[8+r]=s2[r]; sv[12+r]=s3[r]; }
  if (tail) {
    #pragma unroll
    for (int i=0;i<16;++i) {
      const int kl = (i>>2)*16 + g*4 + (i&3);
      if (kl >= TAILNK) sv[i] = -1e30f;
    }
  }
  // max tree in 3-input groups (v_max3)
  const float t0 = fmaxf(fmaxf(sv[0], sv[1]), sv[2]);
  const float t1 = fmaxf(fmaxf(sv[3], sv[4]), sv[5]);
  const float t2 = fmaxf(fmaxf(sv[6], sv[7]), sv[8]);
  const float t3 = fmaxf(fmaxf(sv[9], sv[10]), sv[11]);
  const float t4 = fmaxf(fmaxf(sv[12], sv[13]), sv[14]);
  const float mx = fmaxf(fmaxf(fmaxf(t0, t1), t2), fmaxf(fmaxf(t3, t4), sv[15]));
  // T13: rescale only when running max must grow (wave-uniform branch)
  if (!__all(mx <= m + 8.f)) {
    float mm = fmaxf(mx, __shfl_xor(mx, 16));
    mm = fmaxf(mm, __shfl_xor(mm, 32));
    const float mn = fmaxf(m, mm);
    const float scl = exp2_fast(m - mn);   // first tile: exp2(-inf)=0
    m = mn;
    lacc[0] *= scl;                        // only [0] is ever read
    #pragma unroll
    for (int r=0;r<4;++r){ oA[r]*=scl; oB[r]*=scl; }
  }
  float p[16];
  #pragma unroll
  for (int i=0;i<16;++i) p[i] = exp2_fast(sv[i]-m);
  union { unsigned u[4]; bf16x8 v; } b0, b1;
  #pragma unroll
  for (int i=0;i<4;++i) {
    b0.u[i] = cvt_pk_bf16(p[2*i],   p[2*i+1]);
    b1.u[i] = cvt_pk_bf16(p[8+2*i], p[8+2*i+1]);
  }
  oA = MFMA(A0lo, b0.v, oA, 0,0,0);
  oA = MFMA(A0hi, b1.v, oA, 0,0,0);
  oB = MFMA(A1lo, b0.v, oB, 0,0,0);
  oB = MFMA(A1hi, b1.v, oB, 0,0,0);
  lacc = MFMA(ones, b0.v, lacc, 0,0,0);   // row-sums: l += sum_k p[k]
  lacc = MFMA(ones, b1.v, lacc, 0,0,0);
}

// ---------------- bf16 MFMA flash attention (round-9 proven): 1-wave, 32 q/wave ----
__global__ __launch_bounds__(64) void k_flash6(
    const short* __restrict__ Qbf, const short* __restrict__ Kbf,
    const short* __restrict__ Vf, short* __restrict__ opart,
    float* __restrict__ mlp)
{
  const int lane = threadIdx.x;
  const int g = lane >> 4, c = lane & 15;
  const int flat = blockIdx.x;
  const int p  = flat % 80;
  const int qb = flat / 80;
  const int h  = p & 7;
  const int sp = p >> 3;
  const int q0 = qb * 32;
  const int qa  = min(q0 +      c, NQ-1);
  const int qb2 = min(q0 + 16 + c, NQ-1);
  const bf16x8 qf0 = *(const bf16x8*)(Qbf + (size_t)qa *CDIM + h*DH + g*8);
  const bf16x8 qf1 = *(const bf16x8*)(Qbf + (size_t)qb2*CDIM + h*DH + g*8);
  bf16x8 ones;
  #pragma unroll
  for (int i=0;i<8;++i) ones[i] = (short)0x3F80;
  const int kbase = sp*KPS;
  const size_t doff = (size_t)h*DH + g*8;
  const short* kbp = Kbf + (size_t)(kbase + c)*CDIM + doff;
  const short* vfp = Vf + (size_t)(sp*NH + h)*(TILES*2048) + lane*8;
  const f32x4 z = {0.f,0.f,0.f,0.f};
  f32x4 o00 = z, o01 = z, o10 = z, o11 = z;
  f32x4 lacc0 = z, lacc1 = z;
  float m0v = -INFINITY, m1v = -INFINITY;

  bf16x8 kc0 = *(const bf16x8*)(kbp);
  bf16x8 kc1 = *(const bf16x8*)(kbp + (size_t)16*CDIM);
  bf16x8 kc2 = *(const bf16x8*)(kbp + (size_t)32*CDIM);
  bf16x8 kc3 = *(const bf16x8*)(kbp + (size_t)48*CDIM);

  #pragma unroll
  for (int t = 0; t < FULLT; ++t) {
    const int kt = t*64;
    const f32x4 s00 = MFMA(kc0, qf0, z, 0,0,0);
    const f32x4 s01 = MFMA(kc1, qf0, z, 0,0,0);
    const f32x4 s02 = MFMA(kc2, qf0, z, 0,0,0);
    const f32x4 s03 = MFMA(kc3, qf0, z, 0,0,0);
    const f32x4 s10 = MFMA(kc0, qf1, z, 0,0,0);
    const f32x4 s11 = MFMA(kc1, qf1, z, 0,0,0);
    const f32x4 s12 = MFMA(kc2, qf1, z, 0,0,0);
    const f32x4 s13 = MFMA(kc3, qf1, z, 0,0,0);
    if (t+1 < FULLT) {
      kc0 = *(const bf16x8*)(kbp + (size_t)(kt+64)*CDIM);
      kc1 = *(const bf16x8*)(kbp + (size_t)(kt+80)*CDIM);
      kc2 = *(const bf16x8*)(kbp + (size_t)(kt+96)*CDIM);
      kc3 = *(const bf16x8*)(kbp + (size_t)(kt+112)*CDIM);
    }
    const short* vt = vfp + (size_t)t*2048;
    const bf16x8 A0lo = *(const bf16x8*)(vt       );
    const bf16x8 A1lo = *(const bf16x8*)(vt +  512);
    const bf16x8 A0hi = *(const bf16x8*)(vt + 1024);
    const bf16x8 A1hi = *(const bf16x8*)(vt + 1536);
    softmax_pv(s00,s01,s02,s03, false, g, m0v, lacc0, o00, o01, A0lo, A0hi, A1lo, A1hi, ones);
    softmax_pv(s10,s11,s12,s13, false, g, m1v, lacc1, o10, o11, A0lo, A0hi, A1lo, A1hi, ones);
  }
  { // tail: 52 valid keys; K addr clamped, scores masked, Vf zero-filled by repack
    const int kt = FULLT*64;
    const int ka0 = min(kbase + kt +      c, NKV-1);
    const int ka1 = min(kbase + kt + 16 + c, NKV-1);
    const int ka2 = min(kbase + kt + 32 + c, NKV-1);
    const int ka3 = min(kbase + kt + 48 + c, NKV-1);
    const bf16x8 kf0 = *(const bf16x8*)(Kbf + (size_t)ka0*CDIM + doff);
    const bf16x8 kf1 = *(const bf16x8*)(Kbf + (size_t)ka1*CDIM + doff);
    const bf16x8 kf2 = *(const bf16x8*)(Kbf + (size_t)ka2*CDIM + doff);
    const bf16x8 kf3 = *(const bf16x8*)(Kbf + (size_t)ka3*CDIM + doff);
    const f32x4 s00 = MFMA(kf0, qf0, z, 0,0,0);
    const f32x4 s01 = MFMA(kf1, qf0, z, 0,0,0);
    const f32x4 s02 = MFMA(kf2, qf0, z, 0,0,0);
    const f32x4 s03 = MFMA(kf3, qf0, z, 0,0,0);
    const f32x4 s10 = MFMA(kf0, qf1, z, 0,0,0);
    const f32x4 s11 = MFMA(kf1, qf1, z, 0,0,0);
    const f32x4 s12 = MFMA(kf2, qf1, z, 0,0,0);
    const f32x4 s13 = MFMA(kf3, qf1, z, 0,0,0);
    const short* vt = vfp + (size_t)FULLT*2048;
    const bf16x8 A0lo = *(const bf16x8*)(vt       );
    const bf16x8 A1lo = *(const bf16x8*)(vt +  512);
    const bf16x8 A0hi = *(const bf16x8*)(vt + 1024);
    const bf16x8 A1hi = *(const bf16x8*)(vt + 1536);
    softmax_pv(s00,s01,s02,s03, true, g, m0v, lacc0, o00, o01, A0lo, A0hi, A1lo, A1hi, ones);
    softmax_pv(s10,s11,s12,s13, true, g, m1v, lacc1, o10, o11, A0lo, A0hi, A1lo, A1hi, ones);
  }
  const size_t ob0 = (size_t)(sp*NH + h)*NQ;
  const int qw0 = q0 + c;
  if (qw0 < NQ) {
    const size_t b = (ob0 + qw0)*DH;
    #pragma unroll
    for (int r=0;r<4;++r) {
      opart[b +      g*4 + r] = f2bf(o00[r]);
      opart[b + 16 + g*4 + r] = f2bf(o01[r]);
    }
    if (g == 0) { mlp[(ob0 + qw0)*2] = m0v; mlp[(ob0 + qw0)*2+1] = lacc0[0]; }
  }
  const int qw1 = q0 + 16 + c;
  if (qw1 < NQ) {
    const size_t b = (ob0 + qw1)*DH;
    #pragma unroll
    for (int r=0;r<4;++r) {
      opart[b +      g*4 + r] = f2bf(o10[r]);
      opart[b + 16 + g*4 + r] = f2bf(o11[r]);
    }
    if (g == 0) { mlp[(ob0 + qw1)*2] = m1v; mlp[(ob0 + qw1)*2+1] = lacc1[0]; }
  }
}

// ---------------- row LayerNorm ----------------
__global__ __launch_bounds__(256) void k_ln(
    const float* __restrict__ x, const float* __restrict__ g,
    const float* __restrict__ b, const float* __restrict__ post_res,
    float* __restrict__ out)
{
  const int row = blockIdx.x, c = threadIdx.x;
  const size_t idx = (size_t)row*CDIM + c;
  const float v = x[idx];
  __shared__ float red[4];
  float s = v;
  #pragma unroll
  for (int m = 1; m < 64; m <<= 1) s += __shfl_xor(s, m);
  if ((c & 63) == 0) red[c >> 6] = s;
  __syncthreads();
  const float mean = (red[0]+red[1]+red[2]+red[3]) * (1.f/256.f);
  const float dv = v - mean;
  __syncthreads();
  float s2 = dv*dv;
  #pragma unroll
  for (int m = 1; m < 64; m <<= 1) s2 += __shfl_xor(s2, m);
  if ((c & 63) == 0) red[c >> 6] = s2;
  __syncthreads();
  const float var = (red[0]+red[1]+red[2]+red[3]) * (1.f/256.f);
  float o = dv * rsqrtf(var + 1e-5f) * g[c] + b[c];
  if (post_res) o += post_res[idx];
  out[idx] = o;
}

// ---------------- fused attn_w GEMV + softmax(24) + sampling + agg ----------------
__global__ __launch_bounds__(256) void k_sample_agg(
    const float* __restrict__ q1, const unsigned short* __restrict__ imgT,
    const float* __restrict__ l2i, const float* __restrict__ awW,
    const float* __restrict__ awb, float* __restrict__ agg)
{
  const int q = blockIdx.x, tid = threadIdx.x;
  __shared__ float qrow[256];
  __shared__ float wl[24];
  __shared__ float fwx[24], fwy[24];
  __shared__ int iv[24], ix[24], iy[24];
  qrow[tid] = q1[(size_t)q*CDIM + tid];
  __syncthreads();
  if (tid < 192) {
    const int e = tid >> 3, s2 = tid & 7;
    float acc = 0.f;
    for (int c = s2; c < 256; c += 8) acc += qrow[c]*awW[e*256 + c];
    acc += __shfl_xor(acc,1);
    acc += __shfl_xor(acc,2);
    acc += __shfl_xor(acc,4);
    if (s2 == 0) wl[e] = acc + awb[e];
  }
  if (tid < 24) {
    const int e = tid, n = e >> 2, z = e & 3;
    const int iyq = q / 50, jxq = q % 50;
    const float rx = (jxq + 0.5f)*(1.f/50.f);
    const float ry = (iyq + 0.5f)*(1.f/50.f);
    const float rz = (z + 0.5f)*0.25f;
    const float X = rx*102.4f - 51.2f;
    const float Y = ry*102.4f - 51.2f;
    const float Z = rz*8.f - 5.f;
    const float* L = l2i + n*16;
    const float cx = L[0]*X + L[1]*Y + L[2]*Z  + L[3];
    const float cy = L[4]*X + L[5]*Y + L[6]*Z  + L[7];
    const float cd = L[8]*X + L[9]*Y + L[10]*Z + L[11];
    const float dn = fmaxf(cd, 1e-5f);
    const float u = cx/dn, vv = cy/dn;
    const float gx = (u*(1.f/49.f) - 0.5f)*2.f;
    const float gy = (vv*(1.f/27.f) - 0.5f)*2.f;
    const int ok = (cd > 1e-5f) && (gx > -1.f) && (gx < 1.f) && (gy > -1.f) && (gy < 1.f);
    const float xf = ((gx + 1.f)*50.f - 1.f)*0.5f;
    const float yf = ((gy + 1.f)*28.f - 1.f)*0.5f;
    const float x0f = floorf(xf), y0f = floorf(yf);
    iv[e] = ok; ix[e] = (int)x0f; iy[e] = (int)y0f;
    fwx[e] = xf - x0f; fwy[e] = yf - y0f;
  }
  __syncthreads();
  float mx = -INFINITY;
  #pragma unroll
  for (int e = 0; e < 24; ++e) mx = fmaxf(mx, wl[e]);
  float se = 0.f;
  #pragma unroll
  for (int e = 0; e < 24; ++e) se += __expf(wl[e]-mx);
  const float inv = 1.f/se;
  const int c = tid;
  float acc = 0.f;
  #pragma unroll
  for (int e = 0; e < 24; ++e) {
    if (!iv[e]) continue;
    const float w = __expf(wl[e]-mx)*inv;
    const int n = e >> 2;
    const int x0 = ix[e], y0 = iy[e];
    const float wx = fwx[e], wy = fwy[e];
    const size_t base = (size_t)(n*28)*50;
    float v00 = (x0  >=0 && x0  <50 && y0  >=0 && y0  <28) ? bf2f(imgT[((base + (size_t)y0*50     + x0  ))*CDIM + c]) : 0.f;
    float v10 = (x0+1>=0 && x0+1<50 && y0  >=0 && y0  <28) ? bf2f(imgT[((base + (size_t)y0*50     + x0+1))*CDIM + c]) : 0.f;
    float v01 = (x0  >=0 && x0  <50 && y0+1>=0 && y0+1<28) ? bf2f(imgT[((base + (size_t)(y0+1)*50 + x0  ))*CDIM + c]) : 0.f;
    float v11 = (x0+1>=0 && x0+1<50 && y0+1>=0 && y0+1<28) ? bf2f(imgT[((base + (size_t)(y0+1)*50 + x0+1))*CDIM + c]) : 0.f;
    acc += w * ((v00*(1.f-wx) + v10*wx)*(1.f-wy) + (v01*(1.f-wx) + v11*wx)*wy);
  }
  agg[(size_t)q*CDIM + c] = acc;
}

// ---------------- launcher ----------------
extern "C" void kernel_launch(void* const* d_in, const int* in_sizes, int n_in,
                              void* d_out, int out_size, void* d_ws, size_t ws_size,
                              hipStream_t stream)
{
  const float* query = (const float*)d_in[0];
  const float* prev  = (const float*)d_in[1];
  const float* img   = (const float*)d_in[2];
  const float* ego   = (const float*)d_in[3];
  const float* l2i   = (const float*)d_in[4];
  const float* awW   = (const float*)d_in[5];
  const float* awb   = (const float*)d_in[6];
  const float* scab  = (const float*)d_in[8];
  const float* inb   = (const float*)d_in[10];
  const float* mob   = (const float*)d_in[12];
  const float* n1g   = (const float*)d_in[13];
  const float* n1b   = (const float*)d_in[14];
  const float* fb1   = (const float*)d_in[16];
  const float* fb2   = (const float*)d_in[18];
  const float* n2g   = (const float*)d_in[19];
  const float* n2b   = (const float*)d_in[20];
  float* out = (float*)d_out;
  float* ws  = (float*)d_ws;

  // ---- workspace layout (float offsets, round-9 proven); total 8,505,472 f = 34.0 MB ----
  float* kv    = ws;                        // [5000,256] f32   [0,        1280000)
  short* Qbf   = (short*)(ws + 1280000);    // [2500,256] bf16  [1280000,  1600000)
  short* Kbf   = (short*)(ws + 1600000);    // [5000,256] bf16  [1600000,  2240000)
  short* VbfT  = (short*)(ws + 2240000);    // [256,5000] bf16  [2240000,  2880000)
  short* Vf    = (short*)(ws + 2880000);    // 1,310,720 bf16   [2880000,  3535360)
  short* opart = (short*)(ws + 3535360);    // [10,8,2500,32]   [3535360,  6735360)
  float* mlp   = ws + 6735360;              // [10,8,2500,2]    [6735360,  7135360)
  short* wf    = (short*)(ws + 7135360);    // 589,824 bf16     [7135360,  7430272)
  unsigned short* imgT = (unsigned short*)(ws + 7430272); // [6,28,50,256] [7430272, 8505472)
  // phase B reuse (disjoint per dispatch; opart/mlp live until moW GEMM):
  float* tmp1  = ws;                        // [0,       640000)  (kv dead)
  float* q1    = ws +  640000;              // [640000, 1280000)  (kv dead)
  float* aggb  = ws + 1280000;              // [1280000,1920000)  (Qbf/Kbf-head dead)
  float* q2    = ws + 1920000;              // [1920000,2560000)  (Kbf-tail/VbfT-head dead)
  float* hbuf  = ws + 2560000;              // [2560000,3840000)  (VbfT/Vf/opart-head dead)
  float* h2    = ws + 3840000;              // [3840000,4480000)  (opart dead)

  const float qscale = 0.2550727452794943f;  // (1/sqrt(32)) * log2(e)

  k_prep<<<5456, 256, 0, stream>>>(query, prev, ego, kv, img, imgT,
                                   (const float*)d_in[9], (const float*)d_in[11],
                                   (const float*)d_in[7], (const float*)d_in[15],
                                   (const float*)d_in[17], wf);
  k_gemm_qkv<<<dim3(12,157), 256, 0, stream>>>(kv, wf, inb, Qbf, Kbf, VbfT, qscale);
  k_repack_v<<<5120, 256, 0, stream>>>(VbfT, Vf);
  k_flash6<<<79*80, 64, 0, stream>>>(Qbf, Kbf, Vf, opart, mlp);
  // moW GEMM with A = combine(opart, mlp) fused into staging; res = query
  k_gemm<<<dim3(4,79), 256, 0, stream>>>(nullptr, wf + 196608, mob, query, tmp1, nullptr,
                                         opart, mlp, NQ, 256, 256, 0, 0, 1, 1.0f);
  k_ln<<<NQ, 256, 0, stream>>>(tmp1, n1g, n1b, nullptr, q1);
  k_sample_agg<<<NQ, 256, 0, stream>>>(q1, imgT, l2i, awW, awb, aggb);
  k_gemm<<<dim3(4,79), 256, 0, stream>>>(aggb, wf + 262144, scab, q1, q2, nullptr,
                                         nullptr, nullptr, NQ, 256, 256, 0, 0, 0, 1.0f);
  k_gemm<<<dim3(8,79), 256, 0, stream>>>(q2, wf + 327680, fb1, nullptr, hbuf, nullptr,
                                         nullptr, nullptr, NQ, 512, 256, 1, 0, 0, 1.0f);
  k_gemm<<<dim3(4,79), 256, 0, stream>>>(hbuf, wf + 458752, fb2, nullptr, h2, nullptr,
                                         nullptr, nullptr, NQ, 256, 512, 0, 0, 0, 1.0f);
  k_ln<<<NQ, 256, 0, stream>>>(h2, n2g, n2b, q2, out);
}

// Round 16
// 138.261 us; speedup vs baseline: 1.4142x; 1.0184x over previous
//
#include <hip/hip_runtime.h>
#include <hip/hip_bf16.h>
#include <math.h>

#define NQ   2500
#define CDIM 256
#define NKV  5000
#define NH   8
#define DH   32
#define SPLITS 10
#define KPS   500          // keys per split
#define FULLT 7            // 7 full 64-key tiles
#define TILES 8            // 7 full + 1 tail
#define TAILNK 52          // 500 - 7*64

typedef __attribute__((ext_vector_type(8))) short bf16x8;
typedef __attribute__((ext_vector_type(4))) short short4v;
typedef __attribute__((ext_vector_type(4))) float f32x4;

#define MFMA __builtin_amdgcn_mfma_f32_16x16x32_bf16

__device__ __forceinline__ short f2bf(float f) {          // RNE
  union { float f; unsigned u; } v; v.f = f;
  unsigned r = v.u + 0x7FFFu + ((v.u >> 16) & 1u);
  return (short)(r >> 16);
}
__device__ __forceinline__ float bf2f(unsigned short s) {
  union { unsigned u; float f; } x; x.u = ((unsigned)s) << 16; return x.f;
}
__device__ __forceinline__ unsigned cvt_pk_bf16(float a, float b) { // [lo=a, hi=b] RNE
  unsigned r;
  asm("v_cvt_pk_bf16_f32 %0, %1, %2" : "=v"(r) : "v"(a), "v"(b));
  return r;
}
__device__ __forceinline__ float exp2_fast(float x) {
  float r; asm("v_exp_f32 %0, %1" : "=v"(r) : "v"(x)); return r;
}

// ============ fused prep: build_kv | transpose_img | prep_w (round-9 proven) ============
__global__ __launch_bounds__(256) void k_prep(
    const float* __restrict__ query, const float* __restrict__ prev,
    const float* __restrict__ ego, float* __restrict__ kv,
    const float* __restrict__ img, unsigned short* __restrict__ imgT,
    const float* __restrict__ inW, const float* __restrict__ moW,
    const float* __restrict__ scaW, const float* __restrict__ fW1,
    const float* __restrict__ fW2, short* __restrict__ wf)
{
  const int gid = blockIdx.x, tid = threadIdx.x;
  if (gid < NKV) {
    const int row = gid, c = tid;
    if (row < NQ) { kv[(size_t)row*CDIM + c] = query[(size_t)row*CDIM + c]; return; }
    int n = row - NQ;
    float txm = ego[3], tym = ego[7];
    float yaw = atan2f(ego[4], ego[0]);
    float cs = cosf(yaw), sn = sinf(yaw);
    float dx = txm * (1.f/51.2f), dy = tym * (1.f/51.2f);
    int i = n / 50, j = n % 50;
    float gx = (2.f*j + 1.f)*(1.f/50.f) - 1.f;
    float gy = (2.f*i + 1.f)*(1.f/50.f) - 1.f;
    float px = cs*gx - sn*gy + dx;
    float py = sn*gx + cs*gy + dy;
    float xf = ((px + 1.f)*50.f - 1.f)*0.5f;
    float yf = ((py + 1.f)*50.f - 1.f)*0.5f;
    float x0f = floorf(xf), y0f = floorf(yf);
    int x0 = (int)x0f, y0 = (int)y0f;
    float wx = xf - x0f, wy = yf - y0f;
    float v00 = (x0  >=0 && x0  <50 && y0  >=0 && y0  <50) ? prev[((size_t)(y0*50+x0      ))*CDIM + c] : 0.f;
    float v10 = (x0+1>=0 && x0+1<50 && y0  >=0 && y0  <50) ? prev[((size_t)(y0*50+x0+1    ))*CDIM + c] : 0.f;
    float v01 = (x0  >=0 && x0  <50 && y0+1>=0 && y0+1<50) ? prev[((size_t)((y0+1)*50+x0  ))*CDIM + c] : 0.f;
    float v11 = (x0+1>=0 && x0+1<50 && y0+1>=0 && y0+1<50) ? prev[((size_t)((y0+1)*50+x0+1))*CDIM + c] : 0.f;
    float v = (v00*(1.f-wx) + v10*wx)*(1.f-wy) + (v01*(1.f-wx) + v11*wx)*wy;
    kv[(size_t)row*CDIM + c] = v;
    return;
  }
  if (gid < NKV + 168) {
    const int b = gid - NKV;          // n*28 + y
    const int n = b / 28, y = b % 28;
    const int c = tid;
    for (int x = 0; x < 50; ++x)
      imgT[((size_t)((n*28 + y)*50 + x))*CDIM + c] =
        (unsigned short)f2bf(img[((size_t)(n*CDIM + c)*28 + y)*50 + x]);
    return;
  }
  {
    // weight fragments: wf[obase + ((n>>4)*(K/8) + (k>>3))*128 + (n&15)*8 + j]
    const int id = (gid - NKV - 168)*256 + tid;
    if (id >= 73728) return;
    const int s = id*8;
    const float* src; int off, K, obase;
    if      (s < 65536)  { src = inW;          off = s;          K = 256; obase = 0; }
    else if (s < 131072) { src = inW + 65536;  off = s - 65536;  K = 256; obase = 65536; }
    else if (s < 196608) { src = inW + 131072; off = s - 131072; K = 256; obase = 131072; }
    else if (s < 262144) { src = moW;          off = s - 196608; K = 256; obase = 196608; }
    else if (s < 327680) { src = scaW;         off = s - 262144; K = 256; obase = 262144; }
    else if (s < 458752) { src = fW1;          off = s - 327680; K = 256; obase = 327680; }
    else                 { src = fW2;          off = s - 458752; K = 512; obase = 458752; }
    const int n = off / K, k = off - n*K;
    short4v lo, hi;
    #pragma unroll
    for (int j = 0; j < 4; ++j) { lo[j] = f2bf(src[off+j]); hi[j] = f2bf(src[off+4+j]); }
    short* dst = wf + obase + (size_t)((n>>4)*(K>>3) + (k>>3))*128 + (n&15)*8;
    *(short4v*)dst = lo;
    *(short4v*)(dst+4) = hi;
  }
}

// ============ fused QKV GEMM (round-9 proven): -> Qbf / Kbf / VbfT[256][5000] ============
__global__ __launch_bounds__(256) void k_gemm_qkv(
    const float* __restrict__ A, const short* __restrict__ Wf,
    const float* __restrict__ bias, short* __restrict__ Qbf,
    short* __restrict__ Kbf, short* __restrict__ VbfT, float qscale)
{
  __shared__ short Abf[8][33][8];
  const int tid = threadIdx.x;
  const int lane = tid & 63, wid = tid >> 6;
  const int wm = wid >> 1, wn = wid & 1;
  const int g = lane >> 4, c = lane & 15;
  const int m0 = blockIdx.y << 5, n0 = blockIdx.x << 6;
  if (n0 < 256 && m0 >= NQ) return;    // block-uniform early out
  const int srow = tid >> 3, skq = tid & 7;
  const short* wfa = Wf + (size_t)((n0 + wn*32) >> 4)       * 32 * 128 + c*8;
  const short* wfb = Wf + (size_t)(((n0 + wn*32) >> 4) + 1) * 32 * 128 + c*8;
  f32x4 acc0 = {0.f,0.f,0.f,0.f}, acc1 = acc0;
  for (int k0 = 0; k0 < 256; k0 += 64) {
    const float* ap = A + (size_t)(m0+srow)*256 + k0 + skq*8;
    const float4 fa0 = *(const float4*)ap;
    const float4 fa1 = *(const float4*)(ap+4);
    __syncthreads();
    union { unsigned u[4]; bf16x8 v; } pa;
    pa.u[0] = cvt_pk_bf16(fa0.x, fa0.y);  pa.u[1] = cvt_pk_bf16(fa0.z, fa0.w);
    pa.u[2] = cvt_pk_bf16(fa1.x, fa1.y);  pa.u[3] = cvt_pk_bf16(fa1.z, fa1.w);
    *(bf16x8*)&Abf[skq][srow][0] = pa.v;
    __syncthreads();
    #pragma unroll
    for (int s = 0; s < 2; ++s) {
      const int kq = (k0 >> 3) + s*4 + g;
      const bf16x8 fA  = *(const bf16x8*)&Abf[s*4+g][wm*16 + c][0];
      const bf16x8 fW0 = *(const bf16x8*)(wfa + (size_t)kq*128);
      const bf16x8 fW1 = *(const bf16x8*)(wfb + (size_t)kq*128);
      acc0 = MFMA(fA, fW0, acc0, 0,0,0);
      acc1 = MFMA(fA, fW1, acc1, 0,0,0);
    }
  }
  const int nc0 = n0 + wn*32 + c, nc1 = nc0 + 16;
  const float b0v = bias[nc0], b1v = bias[nc1];
  #pragma unroll
  for (int r = 0; r < 4; ++r) {
    const int m = m0 + wm*16 + g*4 + r;
    if (m >= NKV) continue;
    const float v0 = acc0[r] + b0v;
    const float v1 = acc1[r] + b1v;
    if (nc0 < 256) {
      if (m < NQ) {
        Qbf[(size_t)m*256 + nc0] = f2bf(v0*qscale);
        Qbf[(size_t)m*256 + nc1] = f2bf(v1*qscale);
      }
    } else if (nc0 < 512) {
      Kbf[(size_t)m*256 + nc0 - 256] = f2bf(v0);
      Kbf[(size_t)m*256 + nc1 - 256] = f2bf(v1);
    } else {
      VbfT[(size_t)(nc0 - 512)*NKV + m] = f2bf(v0);
      VbfT[(size_t)(nc1 - 512)*NKV + m] = f2bf(v1);
    }
  }
}

// ---------------- VbfT [256][5000] -> Vf PV-fragments (round-9 proven) ----------------
__global__ __launch_bounds__(256) void k_repack_v(
    const short* __restrict__ VbfT, short* __restrict__ Vf)
{
  const int idx = blockIdx.x*256 + threadIdx.x;   // 5120 * 256 = 1,310,720 exact
  const int j    = idx & 7;
  const int lane = (idx >> 3) & 63;
  const int i    = (idx >> 9) & 1;
  const int kt2  = (idx >> 10) & 1;
  const int t    = (idx >> 11) & 7;
  const int h    = (idx >> 14) & 7;
  const int sp   = idx >> 17;
  const int gg = lane >> 4, cc = lane & 15;
  const int ko32 = ((j >> 2) << 4) | (gg << 2) | (j & 3);
  const int kin = t*64 + kt2*32 + ko32;
  const int d = i*16 + cc;
  short v = 0;
  if (kin < KPS) v = VbfT[(size_t)(h*32 + d)*NKV + sp*KPS + kin];
  Vf[idx] = v;
}

// ---------------- generic MFMA GEMM (frag-W); amode 1 = A from combine(opart,mlp) ----
// (round-11/13 proven verbatim)
__global__ __launch_bounds__(256) void k_gemm(
    const float* __restrict__ A, const short* __restrict__ Wf,
    const float* __restrict__ bias, const float* __restrict__ res,
    float* __restrict__ C, short* __restrict__ Cb,
    const short* __restrict__ opart, const float* __restrict__ mlp,
    int M, int N, int K, int relu, int mode, int amode, float scale)
{
  __shared__ short Abf[8][33][8];
  const int tid = threadIdx.x;
  const int lane = tid & 63, wid = tid >> 6;
  const int wm = wid >> 1, wn = wid & 1;
  const int g = lane >> 4, c = lane & 15;
  const int m0 = blockIdx.y << 5, n0 = blockIdx.x << 6;
  const int srow = tid >> 3, skq = tid & 7;
  const int kb8 = K >> 3;
  const short* wfa = Wf + (size_t)((n0 + wn*32) >> 4)       * kb8 * 128 + c*8;
  const short* wfb = Wf + (size_t)(((n0 + wn*32) >> 4) + 1) * kb8 * 128 + c*8;
  f32x4 acc0 = {0.f,0.f,0.f,0.f}, acc1 = acc0;
  const float4 z4 = make_float4(0.f,0.f,0.f,0.f);
  for (int k0 = 0; k0 < K; k0 += 64) {
    float4 fa0 = z4, fa1 = z4;
    const int mrow = m0 + srow;
    if (mrow < M) {
      if (amode == 0) {
        const float* ap = A + (size_t)mrow*K + k0 + skq*8;
        fa0 = *(const float4*)ap; fa1 = *(const float4*)(ap+4);
      } else {
        // A[mrow][c0..c0+7] = combine(opart, mlp) on the fly (exp2 domain)
        const int c0 = k0 + skq*8;
        const int hh = c0 >> 5, dd = c0 & 31;
        float mstar = -INFINITY;
        float ms[SPLITS], ls[SPLITS];
        #pragma unroll
        for (int s = 0; s < SPLITS; ++s) {
          const size_t b = (size_t)(s*NH + hh)*NQ + mrow;
          ms[s] = mlp[b*2]; ls[s] = mlp[b*2+1];
          mstar = fmaxf(mstar, ms[s]);
        }
        float num[8] = {0,0,0,0,0,0,0,0};
        float den = 0.f;
        #pragma unroll
        for (int s = 0; s < SPLITS; ++s) {
          const float e = exp2_fast(ms[s] - mstar);
          den += ls[s]*e;
          const size_t b = (size_t)(s*NH + hh)*NQ + mrow;
          const short* op = opart + b*DH + dd;
          #pragma unroll
          for (int j = 0; j < 8; ++j) num[j] += bf2f((unsigned short)op[j])*e;
        }
        const float inv = 1.f/den;
        fa0.x = num[0]*inv; fa0.y = num[1]*inv; fa0.z = num[2]*inv; fa0.w = num[3]*inv;
        fa1.x = num[4]*inv; fa1.y = num[5]*inv; fa1.z = num[6]*inv; fa1.w = num[7]*inv;
      }
    }
    __syncthreads();
    union { unsigned u[4]; bf16x8 v; } pa;
    pa.u[0] = cvt_pk_bf16(fa0.x, fa0.y);  pa.u[1] = cvt_pk_bf16(fa0.z, fa0.w);
    pa.u[2] = cvt_pk_bf16(fa1.x, fa1.y);  pa.u[3] = cvt_pk_bf16(fa1.z, fa1.w);
    *(bf16x8*)&Abf[skq][srow][0] = pa.v;
    __syncthreads();
    #pragma unroll
    for (int s = 0; s < 2; ++s) {
      const int kq = (k0 >> 3) + s*4 + g;
      const bf16x8 fA  = *(const bf16x8*)&Abf[s*4+g][wm*16 + c][0];
      const bf16x8 fW0 = *(const bf16x8*)(wfa + (size_t)kq*128);
      const bf16x8 fW1 = *(const bf16x8*)(wfb + (size_t)kq*128);
      acc0 = MFMA(fA, fW0, acc0, 0,0,0);
      acc1 = MFMA(fA, fW1, acc1, 0,0,0);
    }
  }
  const int nc0 = n0 + wn*32 + c, nc1 = nc0 + 16;
  const float b0v = bias[nc0], b1v = bias[nc1];
  #pragma unroll
  for (int r = 0; r < 4; ++r) {
    const int m = m0 + wm*16 + g*4 + r;
    if (m >= M) continue;
    float v0 = acc0[r] + b0v;
    float v1 = acc1[r] + b1v;
    if (mode == 0) {
      if (res) { v0 += res[(size_t)m*N + nc0]; v1 += res[(size_t)m*N + nc1]; }
      if (relu) { v0 = fmaxf(v0, 0.f); v1 = fmaxf(v1, 0.f); }
      C[(size_t)m*N + nc0] = v0;
      C[(size_t)m*N + nc1] = v1;
    } else {
      Cb[(size_t)m*N + nc0] = f2bf(v0*scale);
      Cb[(size_t)m*N + nc1] = f2bf(v1*scale);
    }
  }
}

// ---------------- flash softmax+PV (round-9 proven): defer-max, l via ones-MFMA ----------
__device__ __forceinline__ void softmax_pv(
    f32x4 s0, f32x4 s1, f32x4 s2, f32x4 s3, bool tail, int g,
    float& m, f32x4& lacc, f32x4& oA, f32x4& oB,
    bf16x8 A0lo, bf16x8 A0hi, bf16x8 A1lo, bf16x8 A1hi, bf16x8 ones)
{
  float sv[16];
  #pragma unroll
  for (int r=0;r<4;++r){ sv[r]=s0[r]; sv[4+r]=s1[r]; sv[8+r]=s2[r]; sv[12+r]=s3[r]; }
  if (tail) {
    #pragma unroll
    for (int i=0;i<16;++i) {
      const int kl = (i>>2)*16 + g*4 + (i&3);
      if (kl >= TAILNK) sv[i] = -1e30f;
    }
  }
  // max tree in 3-input groups (v_max3)
  const float t0 = fmaxf(fmaxf(sv[0], sv[1]), sv[2]);
  const float t1 = fmaxf(fmaxf(sv[3], sv[4]), sv[5]);
  const float t2 = fmaxf(fmaxf(sv[6], sv[7]), sv[8]);
  const float t3 = fmaxf(fmaxf(sv[9], sv[10]), sv[11]);
  const float t4 = fmaxf(fmaxf(sv[12], sv[13]), sv[14]);
  const float mx = fmaxf(fmaxf(fmaxf(t0, t1), t2), fmaxf(fmaxf(t3, t4), sv[15]));
  // T13: rescale only when running max must grow (wave-uniform branch)
  if (!__all(mx <= m + 8.f)) {
    float mm = fmaxf(mx, __shfl_xor(mx, 16));
    mm = fmaxf(mm, __shfl_xor(mm, 32));
    const float mn = fmaxf(m, mm);
    const float scl = exp2_fast(m - mn);   // first tile: exp2(-inf)=0
    m = mn;
    lacc[0] *= scl;                        // only [0] is ever read
    #pragma unroll
    for (int r=0;r<4;++r){ oA[r]*=scl; oB[r]*=scl; }
  }
  float p[16];
  #pragma unroll
  for (int i=0;i<16;++i) p[i] = exp2_fast(sv[i]-m);
  union { unsigned u[4]; bf16x8 v; } b0, b1;
  #pragma unroll
  for (int i=0;i<4;++i) {
    b0.u[i] = cvt_pk_bf16(p[2*i],   p[2*i+1]);
    b1.u[i] = cvt_pk_bf16(p[8+2*i], p[8+2*i+1]);
  }
  oA = MFMA(A0lo, b0.v, oA, 0,0,0);
  oA = MFMA(A0hi, b1.v, oA, 0,0,0);
  oB = MFMA(A1lo, b0.v, oB, 0,0,0);
  oB = MFMA(A1hi, b1.v, oB, 0,0,0);
  lacc = MFMA(ones, b0.v, lacc, 0,0,0);   // row-sums: l += sum_k p[k]
  lacc = MFMA(ones, b1.v, lacc, 0,0,0);
}

// ---------------- bf16 MFMA flash attention (round-9 proven): 1-wave, 32 q/wave ----
__global__ __launch_bounds__(64) void k_flash6(
    const short* __restrict__ Qbf, const short* __restrict__ Kbf,
    const short* __restrict__ Vf, short* __restrict__ opart,
    float* __restrict__ mlp)
{
  const int lane = threadIdx.x;
  const int g = lane >> 4, c = lane & 15;
  const int flat = blockIdx.x;
  const int p  = flat % 80;
  const int qb = flat / 80;
  const int h  = p & 7;
  const int sp = p >> 3;
  const int q0 = qb * 32;
  const int qa  = min(q0 +      c, NQ-1);
  const int qb2 = min(q0 + 16 + c, NQ-1);
  const bf16x8 qf0 = *(const bf16x8*)(Qbf + (size_t)qa *CDIM + h*DH + g*8);
  const bf16x8 qf1 = *(const bf16x8*)(Qbf + (size_t)qb2*CDIM + h*DH + g*8);
  bf16x8 ones;
  #pragma unroll
  for (int i=0;i<8;++i) ones[i] = (short)0x3F80;
  const int kbase = sp*KPS;
  const size_t doff = (size_t)h*DH + g*8;
  const short* kbp = Kbf + (size_t)(kbase + c)*CDIM + doff;
  const short* vfp = Vf + (size_t)(sp*NH + h)*(TILES*2048) + lane*8;
  const f32x4 z = {0.f,0.f,0.f,0.f};
  f32x4 o00 = z, o01 = z, o10 = z, o11 = z;
  f32x4 lacc0 = z, lacc1 = z;
  float m0v = -INFINITY, m1v = -INFINITY;

  bf16x8 kc0 = *(const bf16x8*)(kbp);
  bf16x8 kc1 = *(const bf16x8*)(kbp + (size_t)16*CDIM);
  bf16x8 kc2 = *(const bf16x8*)(kbp + (size_t)32*CDIM);
  bf16x8 kc3 = *(const bf16x8*)(kbp + (size_t)48*CDIM);

  #pragma unroll
  for (int t = 0; t < FULLT; ++t) {
    const int kt = t*64;
    const f32x4 s00 = MFMA(kc0, qf0, z, 0,0,0);
    const f32x4 s01 = MFMA(kc1, qf0, z, 0,0,0);
    const f32x4 s02 = MFMA(kc2, qf0, z, 0,0,0);
    const f32x4 s03 = MFMA(kc3, qf0, z, 0,0,0);
    const f32x4 s10 = MFMA(kc0, qf1, z, 0,0,0);
    const f32x4 s11 = MFMA(kc1, qf1, z, 0,0,0);
    const f32x4 s12 = MFMA(kc2, qf1, z, 0,0,0);
    const f32x4 s13 = MFMA(kc3, qf1, z, 0,0,0);
    if (t+1 < FULLT) {
      kc0 = *(const bf16x8*)(kbp + (size_t)(kt+64)*CDIM);
      kc1 = *(const bf16x8*)(kbp + (size_t)(kt+80)*CDIM);
      kc2 = *(const bf16x8*)(kbp + (size_t)(kt+96)*CDIM);
      kc3 = *(const bf16x8*)(kbp + (size_t)(kt+112)*CDIM);
    }
    const short* vt = vfp + (size_t)t*2048;
    const bf16x8 A0lo = *(const bf16x8*)(vt       );
    const bf16x8 A1lo = *(const bf16x8*)(vt +  512);
    const bf16x8 A0hi = *(const bf16x8*)(vt + 1024);
    const bf16x8 A1hi = *(const bf16x8*)(vt + 1536);
    softmax_pv(s00,s01,s02,s03, false, g, m0v, lacc0, o00, o01, A0lo, A0hi, A1lo, A1hi, ones);
    softmax_pv(s10,s11,s12,s13, false, g, m1v, lacc1, o10, o11, A0lo, A0hi, A1lo, A1hi, ones);
  }
  { // tail: 52 valid keys; K addr clamped, scores masked, Vf zero-filled by repack
    const int kt = FULLT*64;
    const int ka0 = min(kbase + kt +      c, NKV-1);
    const int ka1 = min(kbase + kt + 16 + c, NKV-1);
    const int ka2 = min(kbase + kt + 32 + c, NKV-1);
    const int ka3 = min(kbase + kt + 48 + c, NKV-1);
    const bf16x8 kf0 = *(const bf16x8*)(Kbf + (size_t)ka0*CDIM + doff);
    const bf16x8 kf1 = *(const bf16x8*)(Kbf + (size_t)ka1*CDIM + doff);
    const bf16x8 kf2 = *(const bf16x8*)(Kbf + (size_t)ka2*CDIM + doff);
    const bf16x8 kf3 = *(const bf16x8*)(Kbf + (size_t)ka3*CDIM + doff);
    const f32x4 s00 = MFMA(kf0, qf0, z, 0,0,0);
    const f32x4 s01 = MFMA(kf1, qf0, z, 0,0,0);
    const f32x4 s02 = MFMA(kf2, qf0, z, 0,0,0);
    const f32x4 s03 = MFMA(kf3, qf0, z, 0,0,0);
    const f32x4 s10 = MFMA(kf0, qf1, z, 0,0,0);
    const f32x4 s11 = MFMA(kf1, qf1, z, 0,0,0);
    const f32x4 s12 = MFMA(kf2, qf1, z, 0,0,0);
    const f32x4 s13 = MFMA(kf3, qf1, z, 0,0,0);
    const short* vt = vfp + (size_t)FULLT*2048;
    const bf16x8 A0lo = *(const bf16x8*)(vt       );
    const bf16x8 A1lo = *(const bf16x8*)(vt +  512);
    const bf16x8 A0hi = *(const bf16x8*)(vt + 1024);
    const bf16x8 A1hi = *(const bf16x8*)(vt + 1536);
    softmax_pv(s00,s01,s02,s03, true, g, m0v, lacc0, o00, o01, A0lo, A0hi, A1lo, A1hi, ones);
    softmax_pv(s10,s11,s12,s13, true, g, m1v, lacc1, o10, o11, A0lo, A0hi, A1lo, A1hi, ones);
  }
  const size_t ob0 = (size_t)(sp*NH + h)*NQ;
  const int qw0 = q0 + c;
  if (qw0 < NQ) {
    const size_t b = (ob0 + qw0)*DH;
    #pragma unroll
    for (int r=0;r<4;++r) {
      opart[b +      g*4 + r] = f2bf(o00[r]);
      opart[b + 16 + g*4 + r] = f2bf(o01[r]);
    }
    if (g == 0) { mlp[(ob0 + qw0)*2] = m0v; mlp[(ob0 + qw0)*2+1] = lacc0[0]; }
  }
  const int qw1 = q0 + 16 + c;
  if (qw1 < NQ) {
    const size_t b = (ob0 + qw1)*DH;
    #pragma unroll
    for (int r=0;r<4;++r) {
      opart[b +      g*4 + r] = f2bf(o10[r]);
      opart[b + 16 + g*4 + r] = f2bf(o11[r]);
    }
    if (g == 0) { mlp[(ob0 + qw1)*2] = m1v; mlp[(ob0 + qw1)*2+1] = lacc1[0]; }
  }
}

// ---------------- row LayerNorm (final LN only) ----------------
__global__ __launch_bounds__(256) void k_ln(
    const float* __restrict__ x, const float* __restrict__ g,
    const float* __restrict__ b, const float* __restrict__ post_res,
    float* __restrict__ out)
{
  const int row = blockIdx.x, c = threadIdx.x;
  const size_t idx = (size_t)row*CDIM + c;
  const float v = x[idx];
  __shared__ float red[4];
  float s = v;
  #pragma unroll
  for (int m = 1; m < 64; m <<= 1) s += __shfl_xor(s, m);
  if ((c & 63) == 0) red[c >> 6] = s;
  __syncthreads();
  const float mean = (red[0]+red[1]+red[2]+red[3]) * (1.f/256.f);
  const float dv = v - mean;
  __syncthreads();
  float s2 = dv*dv;
  #pragma unroll
  for (int m = 1; m < 64; m <<= 1) s2 += __shfl_xor(s2, m);
  if ((c & 63) == 0) red[c >> 6] = s2;
  __syncthreads();
  const float var = (red[0]+red[1]+red[2]+red[3]) * (1.f/256.f);
  float o = dv * rsqrtf(var + 1e-5f) * g[c] + b[c];
  if (post_res) o += post_res[idx];
  out[idx] = o;
}

// ---- fused LN1 + attn_w GEMV + softmax(24) + sampling + agg ----
// Computes q1 = LN(tmp1)*n1g + n1b (written to global for the later residual),
// then the proven sample_agg body on the normalized row.
__global__ __launch_bounds__(256) void k_sample_agg(
    const float* __restrict__ tmp1, const float* __restrict__ n1g,
    const float* __restrict__ n1b, float* __restrict__ q1,
    const unsigned short* __restrict__ imgT,
    const float* __restrict__ l2i, const float* __restrict__ awW,
    const float* __restrict__ awb, float* __restrict__ agg)
{
  const int q = blockIdx.x, tid = threadIdx.x;
  __shared__ float qrow[256];
  __shared__ float red[4];
  __shared__ float wl[24];
  __shared__ float fwx[24], fwy[24];
  __shared__ int iv[24], ix[24], iy[24];
  // ---- LN1 (proven k_ln pattern) ----
  const size_t idx = (size_t)q*CDIM + tid;
  const float v = tmp1[idx];
  float s = v;
  #pragma unroll
  for (int m = 1; m < 64; m <<= 1) s += __shfl_xor(s, m);
  if ((tid & 63) == 0) red[tid >> 6] = s;
  __syncthreads();
  const float mean = (red[0]+red[1]+red[2]+red[3]) * (1.f/256.f);
  const float dv = v - mean;
  __syncthreads();
  float s2 = dv*dv;
  #pragma unroll
  for (int m = 1; m < 64; m <<= 1) s2 += __shfl_xor(s2, m);
  if ((tid & 63) == 0) red[tid >> 6] = s2;
  __syncthreads();
  const float var = (red[0]+red[1]+red[2]+red[3]) * (1.f/256.f);
  const float o = dv * rsqrtf(var + 1e-5f) * n1g[tid] + n1b[tid];
  q1[idx] = o;                 // residual input for the scaW GEMM
  qrow[tid] = o;
  __syncthreads();
  // ---- proven sample_agg body ----
  if (tid < 192) {
    const int e = tid >> 3, s2b = tid & 7;
    float acc = 0.f;
    for (int c = s2b; c < 256; c += 8) acc += qrow[c]*awW[e*256 + c];
    acc += __shfl_xor(acc,1);
    acc += __shfl_xor(acc,2);
    acc += __shfl_xor(acc,4);
    if (s2b == 0) wl[e] = acc + awb[e];
  }
  if (tid < 24) {
    const int e = tid, n = e >> 2, z = e & 3;
    const int iyq = q / 50, jxq = q % 50;
    const float rx = (jxq + 0.5f)*(1.f/50.f);
    const float ry = (iyq + 0.5f)*(1.f/50.f);
    const float rz = (z + 0.5f)*0.25f;
    const float X = rx*102.4f - 51.2f;
    const float Y = ry*102.4f - 51.2f;
    const float Z = rz*8.f - 5.f;
    const float* L = l2i + n*16;
    const float cx = L[0]*X + L[1]*Y + L[2]*Z  + L[3];
    const float cy = L[4]*X + L[5]*Y + L[6]*Z  + L[7];
    const float cd = L[8]*X + L[9]*Y + L[10]*Z + L[11];
    const float dn = fmaxf(cd, 1e-5f);
    const float u = cx/dn, vv = cy/dn;
    const float gx = (u*(1.f/49.f) - 0.5f)*2.f;
    const float gy = (vv*(1.f/27.f) - 0.5f)*2.f;
    const int ok = (cd > 1e-5f) && (gx > -1.f) && (gx < 1.f) && (gy > -1.f) && (gy < 1.f);
    const float xf = ((gx + 1.f)*50.f - 1.f)*0.5f;
    const float yf = ((gy + 1.f)*28.f - 1.f)*0.5f;
    const float x0f = floorf(xf), y0f = floorf(yf);
    iv[e] = ok; ix[e] = (int)x0f; iy[e] = (int)y0f;
    fwx[e] = xf - x0f; fwy[e] = yf - y0f;
  }
  __syncthreads();
  float mx = -INFINITY;
  #pragma unroll
  for (int e = 0; e < 24; ++e) mx = fmaxf(mx, wl[e]);
  float se = 0.f;
  #pragma unroll
  for (int e = 0; e < 24; ++e) se += __expf(wl[e]-mx);
  const float inv = 1.f/se;
  const int c = tid;
  float acc = 0.f;
  #pragma unroll
  for (int e = 0; e < 24; ++e) {
    if (!iv[e]) continue;
    const float w = __expf(wl[e]-mx)*inv;
    const int n = e >> 2;
    const int x0 = ix[e], y0 = iy[e];
    const float wx = fwx[e], wy = fwy[e];
    const size_t base = (size_t)(n*28)*50;
    float v00 = (x0  >=0 && x0  <50 && y0  >=0 && y0  <28) ? bf2f(imgT[((base + (size_t)y0*50     + x0  ))*CDIM + c]) : 0.f;
    float v10 = (x0+1>=0 && x0+1<50 && y0  >=0 && y0  <28) ? bf2f(imgT[((base + (size_t)y0*50     + x0+1))*CDIM + c]) : 0.f;
    float v01 = (x0  >=0 && x0  <50 && y0+1>=0 && y0+1<28) ? bf2f(imgT[((base + (size_t)(y0+1)*50 + x0  ))*CDIM + c]) : 0.f;
    float v11 = (x0+1>=0 && x0+1<50 && y0+1>=0 && y0+1<28) ? bf2f(imgT[((base + (size_t)(y0+1)*50 + x0+1))*CDIM + c]) : 0.f;
    acc += w * ((v00*(1.f-wx) + v10*wx)*(1.f-wy) + (v01*(1.f-wx) + v11*wx)*wy);
  }
  agg[(size_t)q*CDIM + c] = acc;
}

// ---------------- launcher ----------------
extern "C" void kernel_launch(void* const* d_in, const int* in_sizes, int n_in,
                              void* d_out, int out_size, void* d_ws, size_t ws_size,
                              hipStream_t stream)
{
  const float* query = (const float*)d_in[0];
  const float* prev  = (const float*)d_in[1];
  const float* img   = (const float*)d_in[2];
  const float* ego   = (const float*)d_in[3];
  const float* l2i   = (const float*)d_in[4];
  const float* awW   = (const float*)d_in[5];
  const float* awb   = (const float*)d_in[6];
  const float* scab  = (const float*)d_in[8];
  const float* inb   = (const float*)d_in[10];
  const float* mob   = (const float*)d_in[12];
  const float* n1g   = (const float*)d_in[13];
  const float* n1b   = (const float*)d_in[14];
  const float* fb1   = (const float*)d_in[16];
  const float* fb2   = (const float*)d_in[18];
  const float* n2g   = (const float*)d_in[19];
  const float* n2b   = (const float*)d_in[20];
  float* out = (float*)d_out;
  float* ws  = (float*)d_ws;

  // ---- workspace layout (float offsets, round-15 proven); total 8,505,472 f = 34.0 MB ----
  float* kv    = ws;                        // [5000,256] f32   [0,        1280000)
  short* Qbf   = (short*)(ws + 1280000);    // [2500,256] bf16  [1280000,  1600000)
  short* Kbf   = (short*)(ws + 1600000);    // [5000,256] bf16  [1600000,  2240000)
  short* VbfT  = (short*)(ws + 2240000);    // [256,5000] bf16  [2240000,  2880000)
  short* Vf    = (short*)(ws + 2880000);    // 1,310,720 bf16   [2880000,  3535360)
  short* opart = (short*)(ws + 3535360);    // [10,8,2500,32]   [3535360,  6735360)
  float* mlp   = ws + 6735360;              // [10,8,2500,2]    [6735360,  7135360)
  short* wf    = (short*)(ws + 7135360);    // 589,824 bf16     [7135360,  7430272)
  unsigned short* imgT = (unsigned short*)(ws + 7430272); // [6,28,50,256] [7430272, 8505472)
  // phase B reuse (disjoint per dispatch; opart/mlp live until moW GEMM):
  float* tmp1  = ws;                        // [0,       640000)  (kv dead)
  float* q1    = ws +  640000;              // [640000, 1280000)  (kv dead)
  float* aggb  = ws + 1280000;              // [1280000,1920000)  (Qbf/Kbf-head dead)
  float* q2    = ws + 1920000;              // [1920000,2560000)  (Kbf-tail/VbfT-head dead)
  float* hbuf  = ws + 2560000;              // [2560000,3840000)  (VbfT/Vf/opart-head dead)
  float* h2    = ws + 3840000;              // [3840000,4480000)  (opart dead)

  const float qscale = 0.2550727452794943f;  // (1/sqrt(32)) * log2(e)

  k_prep<<<5456, 256, 0, stream>>>(query, prev, ego, kv, img, imgT,
                                   (const float*)d_in[9], (const float*)d_in[11],
                                   (const float*)d_in[7], (const float*)d_in[15],
                                   (const float*)d_in[17], wf);
  k_gemm_qkv<<<dim3(12,157), 256, 0, stream>>>(kv, wf, inb, Qbf, Kbf, VbfT, qscale);
  k_repack_v<<<5120, 256, 0, stream>>>(VbfT, Vf);
  k_flash6<<<79*80, 64, 0, stream>>>(Qbf, Kbf, Vf, opart, mlp);
  // moW GEMM with A = combine(opart, mlp) fused into staging; res = query
  k_gemm<<<dim3(4,79), 256, 0, stream>>>(nullptr, wf + 196608, mob, query, tmp1, nullptr,
                                         opart, mlp, NQ, 256, 256, 0, 0, 1, 1.0f);
  // fused LN1 + sampling/aggregation (writes q1 for residual, aggb)
  k_sample_agg<<<NQ, 256, 0, stream>>>(tmp1, n1g, n1b, q1, imgT, l2i, awW, awb, aggb);
  k_gemm<<<dim3(4,79), 256, 0, stream>>>(aggb, wf + 262144, scab, q1, q2, nullptr,
                                         nullptr, nullptr, NQ, 256, 256, 0, 0, 0, 1.0f);
  k_gemm<<<dim3(8,79), 256, 0, stream>>>(q2, wf + 327680, fb1, nullptr, hbuf, nullptr,
                                         nullptr, nullptr, NQ, 512, 256, 1, 0, 0, 1.0f);
  k_gemm<<<dim3(4,79), 256, 0, stream>>>(hbuf, wf + 458752, fb2, nullptr, h2, nullptr,
                                         nullptr, nullptr, NQ, 256, 512, 0, 0, 0, 1.0f);
  k_ln<<<NQ, 256, 0, stream>>>(h2, n2g, n2b, q2, out);
}

// Round 17
// 138.196 us; speedup vs baseline: 1.4149x; 1.0005x over previous
//
#include <hip/hip_runtime.h>
#include <hip/hip_bf16.h>
#include <math.h>

#define NQ   2500
#define CDIM 256
#define NKV  5000
#define NH   8
#define DH   32
#define SPLITS 10
#define KPS   500          // keys per split
#define FULLT 7            // 7 full 64-key tiles
#define TILES 8            // 7 full + 1 tail
#define TAILNK 52          // 500 - 7*64

typedef __attribute__((ext_vector_type(8))) short bf16x8;
typedef __attribute__((ext_vector_type(4))) short short4v;
typedef __attribute__((ext_vector_type(4))) float f32x4;

#define MFMA __builtin_amdgcn_mfma_f32_16x16x32_bf16

__device__ __forceinline__ short f2bf(float f) {          // RNE
  union { float f; unsigned u; } v; v.f = f;
  unsigned r = v.u + 0x7FFFu + ((v.u >> 16) & 1u);
  return (short)(r >> 16);
}
__device__ __forceinline__ float bf2f(unsigned short s) {
  union { unsigned u; float f; } x; x.u = ((unsigned)s) << 16; return x.f;
}
__device__ __forceinline__ unsigned cvt_pk_bf16(float a, float b) { // [lo=a, hi=b] RNE
  unsigned r;
  asm("v_cvt_pk_bf16_f32 %0, %1, %2" : "=v"(r) : "v"(a), "v"(b));
  return r;
}
__device__ __forceinline__ float exp2_fast(float x) {
  float r; asm("v_exp_f32 %0, %1" : "=v"(r) : "v"(x)); return r;
}

// ============ fused prep: build_kv | transpose_img | prep_w (round-9 proven) ============
__global__ __launch_bounds__(256) void k_prep(
    const float* __restrict__ query, const float* __restrict__ prev,
    const float* __restrict__ ego, float* __restrict__ kv,
    const float* __restrict__ img, unsigned short* __restrict__ imgT,
    const float* __restrict__ inW, const float* __restrict__ moW,
    const float* __restrict__ scaW, const float* __restrict__ fW1,
    const float* __restrict__ fW2, short* __restrict__ wf)
{
  const int gid = blockIdx.x, tid = threadIdx.x;
  if (gid < NKV) {
    const int row = gid, c = tid;
    if (row < NQ) { kv[(size_t)row*CDIM + c] = query[(size_t)row*CDIM + c]; return; }
    int n = row - NQ;
    float txm = ego[3], tym = ego[7];
    float yaw = atan2f(ego[4], ego[0]);
    float cs = cosf(yaw), sn = sinf(yaw);
    float dx = txm * (1.f/51.2f), dy = tym * (1.f/51.2f);
    int i = n / 50, j = n % 50;
    float gx = (2.f*j + 1.f)*(1.f/50.f) - 1.f;
    float gy = (2.f*i + 1.f)*(1.f/50.f) - 1.f;
    float px = cs*gx - sn*gy + dx;
    float py = sn*gx + cs*gy + dy;
    float xf = ((px + 1.f)*50.f - 1.f)*0.5f;
    float yf = ((py + 1.f)*50.f - 1.f)*0.5f;
    float x0f = floorf(xf), y0f = floorf(yf);
    int x0 = (int)x0f, y0 = (int)y0f;
    float wx = xf - x0f, wy = yf - y0f;
    float v00 = (x0  >=0 && x0  <50 && y0  >=0 && y0  <50) ? prev[((size_t)(y0*50+x0      ))*CDIM + c] : 0.f;
    float v10 = (x0+1>=0 && x0+1<50 && y0  >=0 && y0  <50) ? prev[((size_t)(y0*50+x0+1    ))*CDIM + c] : 0.f;
    float v01 = (x0  >=0 && x0  <50 && y0+1>=0 && y0+1<50) ? prev[((size_t)((y0+1)*50+x0  ))*CDIM + c] : 0.f;
    float v11 = (x0+1>=0 && x0+1<50 && y0+1>=0 && y0+1<50) ? prev[((size_t)((y0+1)*50+x0+1))*CDIM + c] : 0.f;
    float v = (v00*(1.f-wx) + v10*wx)*(1.f-wy) + (v01*(1.f-wx) + v11*wx)*wy;
    kv[(size_t)row*CDIM + c] = v;
    return;
  }
  if (gid < NKV + 168) {
    const int b = gid - NKV;          // n*28 + y
    const int n = b / 28, y = b % 28;
    const int c = tid;
    for (int x = 0; x < 50; ++x)
      imgT[((size_t)((n*28 + y)*50 + x))*CDIM + c] =
        (unsigned short)f2bf(img[((size_t)(n*CDIM + c)*28 + y)*50 + x]);
    return;
  }
  {
    // weight fragments: wf[obase + ((n>>4)*(K/8) + (k>>3))*128 + (n&15)*8 + j]
    const int id = (gid - NKV - 168)*256 + tid;
    if (id >= 73728) return;
    const int s = id*8;
    const float* src; int off, K, obase;
    if      (s < 65536)  { src = inW;          off = s;          K = 256; obase = 0; }
    else if (s < 131072) { src = inW + 65536;  off = s - 65536;  K = 256; obase = 65536; }
    else if (s < 196608) { src = inW + 131072; off = s - 131072; K = 256; obase = 131072; }
    else if (s < 262144) { src = moW;          off = s - 196608; K = 256; obase = 196608; }
    else if (s < 327680) { src = scaW;         off = s - 262144; K = 256; obase = 262144; }
    else if (s < 458752) { src = fW1;          off = s - 327680; K = 256; obase = 327680; }
    else                 { src = fW2;          off = s - 458752; K = 512; obase = 458752; }
    const int n = off / K, k = off - n*K;
    short4v lo, hi;
    #pragma unroll
    for (int j = 0; j < 4; ++j) { lo[j] = f2bf(src[off+j]); hi[j] = f2bf(src[off+4+j]); }
    short* dst = wf + obase + (size_t)((n>>4)*(K>>3) + (k>>3))*128 + (n&15)*8;
    *(short4v*)dst = lo;
    *(short4v*)(dst+4) = hi;
  }
}

// ============ fused QKV GEMM (round-9 proven): -> Qbf / Kbf / VbfT[256][5000] ============
__global__ __launch_bounds__(256) void k_gemm_qkv(
    const float* __restrict__ A, const short* __restrict__ Wf,
    const float* __restrict__ bias, short* __restrict__ Qbf,
    short* __restrict__ Kbf, short* __restrict__ VbfT, float qscale)
{
  __shared__ short Abf[8][33][8];
  const int tid = threadIdx.x;
  const int lane = tid & 63, wid = tid >> 6;
  const int wm = wid >> 1, wn = wid & 1;
  const int g = lane >> 4, c = lane & 15;
  const int m0 = blockIdx.y << 5, n0 = blockIdx.x << 6;
  if (n0 < 256 && m0 >= NQ) return;    // block-uniform early out
  const int srow = tid >> 3, skq = tid & 7;
  const short* wfa = Wf + (size_t)((n0 + wn*32) >> 4)       * 32 * 128 + c*8;
  const short* wfb = Wf + (size_t)(((n0 + wn*32) >> 4) + 1) * 32 * 128 + c*8;
  f32x4 acc0 = {0.f,0.f,0.f,0.f}, acc1 = acc0;
  for (int k0 = 0; k0 < 256; k0 += 64) {
    const float* ap = A + (size_t)(m0+srow)*256 + k0 + skq*8;
    const float4 fa0 = *(const float4*)ap;
    const float4 fa1 = *(const float4*)(ap+4);
    __syncthreads();
    union { unsigned u[4]; bf16x8 v; } pa;
    pa.u[0] = cvt_pk_bf16(fa0.x, fa0.y);  pa.u[1] = cvt_pk_bf16(fa0.z, fa0.w);
    pa.u[2] = cvt_pk_bf16(fa1.x, fa1.y);  pa.u[3] = cvt_pk_bf16(fa1.z, fa1.w);
    *(bf16x8*)&Abf[skq][srow][0] = pa.v;
    __syncthreads();
    #pragma unroll
    for (int s = 0; s < 2; ++s) {
      const int kq = (k0 >> 3) + s*4 + g;
      const bf16x8 fA  = *(const bf16x8*)&Abf[s*4+g][wm*16 + c][0];
      const bf16x8 fW0 = *(const bf16x8*)(wfa + (size_t)kq*128);
      const bf16x8 fW1 = *(const bf16x8*)(wfb + (size_t)kq*128);
      acc0 = MFMA(fA, fW0, acc0, 0,0,0);
      acc1 = MFMA(fA, fW1, acc1, 0,0,0);
    }
  }
  const int nc0 = n0 + wn*32 + c, nc1 = nc0 + 16;
  const float b0v = bias[nc0], b1v = bias[nc1];
  #pragma unroll
  for (int r = 0; r < 4; ++r) {
    const int m = m0 + wm*16 + g*4 + r;
    if (m >= NKV) continue;
    const float v0 = acc0[r] + b0v;
    const float v1 = acc1[r] + b1v;
    if (nc0 < 256) {
      if (m < NQ) {
        Qbf[(size_t)m*256 + nc0] = f2bf(v0*qscale);
        Qbf[(size_t)m*256 + nc1] = f2bf(v1*qscale);
      }
    } else if (nc0 < 512) {
      Kbf[(size_t)m*256 + nc0 - 256] = f2bf(v0);
      Kbf[(size_t)m*256 + nc1 - 256] = f2bf(v1);
    } else {
      VbfT[(size_t)(nc0 - 512)*NKV + m] = f2bf(v0);
      VbfT[(size_t)(nc1 - 512)*NKV + m] = f2bf(v1);
    }
  }
}

// ---------------- VbfT [256][5000] -> Vf PV-fragments (round-9 proven) ----------------
__global__ __launch_bounds__(256) void k_repack_v(
    const short* __restrict__ VbfT, short* __restrict__ Vf)
{
  const int idx = blockIdx.x*256 + threadIdx.x;   // 5120 * 256 = 1,310,720 exact
  const int j    = idx & 7;
  const int lane = (idx >> 3) & 63;
  const int i    = (idx >> 9) & 1;
  const int kt2  = (idx >> 10) & 1;
  const int t    = (idx >> 11) & 7;
  const int h    = (idx >> 14) & 7;
  const int sp   = idx >> 17;
  const int gg = lane >> 4, cc = lane & 15;
  const int ko32 = ((j >> 2) << 4) | (gg << 2) | (j & 3);
  const int kin = t*64 + kt2*32 + ko32;
  const int d = i*16 + cc;
  short v = 0;
  if (kin < KPS) v = VbfT[(size_t)(h*32 + d)*NKV + sp*KPS + kin];
  Vf[idx] = v;
}

// ---------------- generic MFMA GEMM (frag-W); amode 1 = A from combine(opart,mlp) ----
// (round-11/13 proven verbatim)
__global__ __launch_bounds__(256) void k_gemm(
    const float* __restrict__ A, const short* __restrict__ Wf,
    const float* __restrict__ bias, const float* __restrict__ res,
    float* __restrict__ C, short* __restrict__ Cb,
    const short* __restrict__ opart, const float* __restrict__ mlp,
    int M, int N, int K, int relu, int mode, int amode, float scale)
{
  __shared__ short Abf[8][33][8];
  const int tid = threadIdx.x;
  const int lane = tid & 63, wid = tid >> 6;
  const int wm = wid >> 1, wn = wid & 1;
  const int g = lane >> 4, c = lane & 15;
  const int m0 = blockIdx.y << 5, n0 = blockIdx.x << 6;
  const int srow = tid >> 3, skq = tid & 7;
  const int kb8 = K >> 3;
  const short* wfa = Wf + (size_t)((n0 + wn*32) >> 4)       * kb8 * 128 + c*8;
  const short* wfb = Wf + (size_t)(((n0 + wn*32) >> 4) + 1) * kb8 * 128 + c*8;
  f32x4 acc0 = {0.f,0.f,0.f,0.f}, acc1 = acc0;
  const float4 z4 = make_float4(0.f,0.f,0.f,0.f);
  for (int k0 = 0; k0 < K; k0 += 64) {
    float4 fa0 = z4, fa1 = z4;
    const int mrow = m0 + srow;
    if (mrow < M) {
      if (amode == 0) {
        const float* ap = A + (size_t)mrow*K + k0 + skq*8;
        fa0 = *(const float4*)ap; fa1 = *(const float4*)(ap+4);
      } else {
        // A[mrow][c0..c0+7] = combine(opart, mlp) on the fly (exp2 domain)
        const int c0 = k0 + skq*8;
        const int hh = c0 >> 5, dd = c0 & 31;
        float mstar = -INFINITY;
        float ms[SPLITS], ls[SPLITS];
        #pragma unroll
        for (int s = 0; s < SPLITS; ++s) {
          const size_t b = (size_t)(s*NH + hh)*NQ + mrow;
          ms[s] = mlp[b*2]; ls[s] = mlp[b*2+1];
          mstar = fmaxf(mstar, ms[s]);
        }
        float num[8] = {0,0,0,0,0,0,0,0};
        float den = 0.f;
        #pragma unroll
        for (int s = 0; s < SPLITS; ++s) {
          const float e = exp2_fast(ms[s] - mstar);
          den += ls[s]*e;
          const size_t b = (size_t)(s*NH + hh)*NQ + mrow;
          const short* op = opart + b*DH + dd;
          #pragma unroll
          for (int j = 0; j < 8; ++j) num[j] += bf2f((unsigned short)op[j])*e;
        }
        const float inv = 1.f/den;
        fa0.x = num[0]*inv; fa0.y = num[1]*inv; fa0.z = num[2]*inv; fa0.w = num[3]*inv;
        fa1.x = num[4]*inv; fa1.y = num[5]*inv; fa1.z = num[6]*inv; fa1.w = num[7]*inv;
      }
    }
    __syncthreads();
    union { unsigned u[4]; bf16x8 v; } pa;
    pa.u[0] = cvt_pk_bf16(fa0.x, fa0.y);  pa.u[1] = cvt_pk_bf16(fa0.z, fa0.w);
    pa.u[2] = cvt_pk_bf16(fa1.x, fa1.y);  pa.u[3] = cvt_pk_bf16(fa1.z, fa1.w);
    *(bf16x8*)&Abf[skq][srow][0] = pa.v;
    __syncthreads();
    #pragma unroll
    for (int s = 0; s < 2; ++s) {
      const int kq = (k0 >> 3) + s*4 + g;
      const bf16x8 fA  = *(const bf16x8*)&Abf[s*4+g][wm*16 + c][0];
      const bf16x8 fW0 = *(const bf16x8*)(wfa + (size_t)kq*128);
      const bf16x8 fW1 = *(const bf16x8*)(wfb + (size_t)kq*128);
      acc0 = MFMA(fA, fW0, acc0, 0,0,0);
      acc1 = MFMA(fA, fW1, acc1, 0,0,0);
    }
  }
  const int nc0 = n0 + wn*32 + c, nc1 = nc0 + 16;
  const float b0v = bias[nc0], b1v = bias[nc1];
  #pragma unroll
  for (int r = 0; r < 4; ++r) {
    const int m = m0 + wm*16 + g*4 + r;
    if (m >= M) continue;
    float v0 = acc0[r] + b0v;
    float v1 = acc1[r] + b1v;
    if (mode == 0) {
      if (res) { v0 += res[(size_t)m*N + nc0]; v1 += res[(size_t)m*N + nc1]; }
      if (relu) { v0 = fmaxf(v0, 0.f); v1 = fmaxf(v1, 0.f); }
      C[(size_t)m*N + nc0] = v0;
      C[(size_t)m*N + nc1] = v1;
    } else {
      Cb[(size_t)m*N + nc0] = f2bf(v0*scale);
      Cb[(size_t)m*N + nc1] = f2bf(v1*scale);
    }
  }
}

// ---------------- flash softmax+PV (round-9 proven): defer-max, l via ones-MFMA ----------
__device__ __forceinline__ void softmax_pv(
    f32x4 s0, f32x4 s1, f32x4 s2, f32x4 s3, bool tail, int g,
    float& m, f32x4& lacc, f32x4& oA, f32x4& oB,
    bf16x8 A0lo, bf16x8 A0hi, bf16x8 A1lo, bf16x8 A1hi, bf16x8 ones)
{
  float sv[16];
  #pragma unroll
  for (int r=0;r<4;++r){ sv[r]=s0[r]; sv[4+r]=s1[r]; sv[8+r]=s2[r]; sv[12+r]=s3[r]; }
  if (tail) {
    #pragma unroll
    for (int i=0;i<16;++i) {
      const int kl = (i>>2)*16 + g*4 + (i&3);
      if (kl >= TAILNK) sv[i] = -1e30f;
    }
  }
  // max tree in 3-input groups (v_max3)
  const float t0 = fmaxf(fmaxf(sv[0], sv[1]), sv[2]);
  const float t1 = fmaxf(fmaxf(sv[3], sv[4]), sv[5]);
  const float t2 = fmaxf(fmaxf(sv[6], sv[7]), sv[8]);
  const float t3 = fmaxf(fmaxf(sv[9], sv[10]), sv[11]);
  const float t4 = fmaxf(fmaxf(sv[12], sv[13]), sv[14]);
  const float mx = fmaxf(fmaxf(fmaxf(t0, t1), t2), fmaxf(fmaxf(t3, t4), sv[15]));
  // T13: rescale only when running max must grow (wave-uniform branch)
  if (!__all(mx <= m + 8.f)) {
    float mm = fmaxf(mx, __shfl_xor(mx, 16));
    mm = fmaxf(mm, __shfl_xor(mm, 32));
    const float mn = fmaxf(m, mm);
    const float scl = exp2_fast(m - mn);   // first tile: exp2(-inf)=0
    m = mn;
    lacc[0] *= scl;                        // only [0] is ever read
    #pragma unroll
    for (int r=0;r<4;++r){ oA[r]*=scl; oB[r]*=scl; }
  }
  float p[16];
  #pragma unroll
  for (int i=0;i<16;++i) p[i] = exp2_fast(sv[i]-m);
  union { unsigned u[4]; bf16x8 v; } b0, b1;
  #pragma unroll
  for (int i=0;i<4;++i) {
    b0.u[i] = cvt_pk_bf16(p[2*i],   p[2*i+1]);
    b1.u[i] = cvt_pk_bf16(p[8+2*i], p[8+2*i+1]);
  }
  oA = MFMA(A0lo, b0.v, oA, 0,0,0);
  oA = MFMA(A0hi, b1.v, oA, 0,0,0);
  oB = MFMA(A1lo, b0.v, oB, 0,0,0);
  oB = MFMA(A1hi, b1.v, oB, 0,0,0);
  lacc = MFMA(ones, b0.v, lacc, 0,0,0);   // row-sums: l += sum_k p[k]
  lacc = MFMA(ones, b1.v, lacc, 0,0,0);
}

// ---------------- bf16 MFMA flash attention (round-9 proven): 1-wave, 32 q/wave ----
__global__ __launch_bounds__(64) void k_flash6(
    const short* __restrict__ Qbf, const short* __restrict__ Kbf,
    const short* __restrict__ Vf, short* __restrict__ opart,
    float* __restrict__ mlp)
{
  const int lane = threadIdx.x;
  const int g = lane >> 4, c = lane & 15;
  const int flat = blockIdx.x;
  const int p  = flat % 80;
  const int qb = flat / 80;
  const int h  = p & 7;
  const int sp = p >> 3;
  const int q0 = qb * 32;
  const int qa  = min(q0 +      c, NQ-1);
  const int qb2 = min(q0 + 16 + c, NQ-1);
  const bf16x8 qf0 = *(const bf16x8*)(Qbf + (size_t)qa *CDIM + h*DH + g*8);
  const bf16x8 qf1 = *(const bf16x8*)(Qbf + (size_t)qb2*CDIM + h*DH + g*8);
  bf16x8 ones;
  #pragma unroll
  for (int i=0;i<8;++i) ones[i] = (short)0x3F80;
  const int kbase = sp*KPS;
  const size_t doff = (size_t)h*DH + g*8;
  const short* kbp = Kbf + (size_t)(kbase + c)*CDIM + doff;
  const short* vfp = Vf + (size_t)(sp*NH + h)*(TILES*2048) + lane*8;
  const f32x4 z = {0.f,0.f,0.f,0.f};
  f32x4 o00 = z, o01 = z, o10 = z, o11 = z;
  f32x4 lacc0 = z, lacc1 = z;
  float m0v = -INFINITY, m1v = -INFINITY;

  bf16x8 kc0 = *(const bf16x8*)(kbp);
  bf16x8 kc1 = *(const bf16x8*)(kbp + (size_t)16*CDIM);
  bf16x8 kc2 = *(const bf16x8*)(kbp + (size_t)32*CDIM);
  bf16x8 kc3 = *(const bf16x8*)(kbp + (size_t)48*CDIM);

  #pragma unroll
  for (int t = 0; t < FULLT; ++t) {
    const int kt = t*64;
    const f32x4 s00 = MFMA(kc0, qf0, z, 0,0,0);
    const f32x4 s01 = MFMA(kc1, qf0, z, 0,0,0);
    const f32x4 s02 = MFMA(kc2, qf0, z, 0,0,0);
    const f32x4 s03 = MFMA(kc3, qf0, z, 0,0,0);
    const f32x4 s10 = MFMA(kc0, qf1, z, 0,0,0);
    const f32x4 s11 = MFMA(kc1, qf1, z, 0,0,0);
    const f32x4 s12 = MFMA(kc2, qf1, z, 0,0,0);
    const f32x4 s13 = MFMA(kc3, qf1, z, 0,0,0);
    if (t+1 < FULLT) {
      kc0 = *(const bf16x8*)(kbp + (size_t)(kt+64)*CDIM);
      kc1 = *(const bf16x8*)(kbp + (size_t)(kt+80)*CDIM);
      kc2 = *(const bf16x8*)(kbp + (size_t)(kt+96)*CDIM);
      kc3 = *(const bf16x8*)(kbp + (size_t)(kt+112)*CDIM);
    }
    const short* vt = vfp + (size_t)t*2048;
    const bf16x8 A0lo = *(const bf16x8*)(vt       );
    const bf16x8 A1lo = *(const bf16x8*)(vt +  512);
    const bf16x8 A0hi = *(const bf16x8*)(vt + 1024);
    const bf16x8 A1hi = *(const bf16x8*)(vt + 1536);
    softmax_pv(s00,s01,s02,s03, false, g, m0v, lacc0, o00, o01, A0lo, A0hi, A1lo, A1hi, ones);
    softmax_pv(s10,s11,s12,s13, false, g, m1v, lacc1, o10, o11, A0lo, A0hi, A1lo, A1hi, ones);
  }
  { // tail: 52 valid keys; K addr clamped, scores masked, Vf zero-filled by repack
    const int kt = FULLT*64;
    const int ka0 = min(kbase + kt +      c, NKV-1);
    const int ka1 = min(kbase + kt + 16 + c, NKV-1);
    const int ka2 = min(kbase + kt + 32 + c, NKV-1);
    const int ka3 = min(kbase + kt + 48 + c, NKV-1);
    const bf16x8 kf0 = *(const bf16x8*)(Kbf + (size_t)ka0*CDIM + doff);
    const bf16x8 kf1 = *(const bf16x8*)(Kbf + (size_t)ka1*CDIM + doff);
    const bf16x8 kf2 = *(const bf16x8*)(Kbf + (size_t)ka2*CDIM + doff);
    const bf16x8 kf3 = *(const bf16x8*)(Kbf + (size_t)ka3*CDIM + doff);
    const f32x4 s00 = MFMA(kf0, qf0, z, 0,0,0);
    const f32x4 s01 = MFMA(kf1, qf0, z, 0,0,0);
    const f32x4 s02 = MFMA(kf2, qf0, z, 0,0,0);
    const f32x4 s03 = MFMA(kf3, qf0, z, 0,0,0);
    const f32x4 s10 = MFMA(kf0, qf1, z, 0,0,0);
    const f32x4 s11 = MFMA(kf1, qf1, z, 0,0,0);
    const f32x4 s12 = MFMA(kf2, qf1, z, 0,0,0);
    const f32x4 s13 = MFMA(kf3, qf1, z, 0,0,0);
    const short* vt = vfp + (size_t)FULLT*2048;
    const bf16x8 A0lo = *(const bf16x8*)(vt       );
    const bf16x8 A1lo = *(const bf16x8*)(vt +  512);
    const bf16x8 A0hi = *(const bf16x8*)(vt + 1024);
    const bf16x8 A1hi = *(const bf16x8*)(vt + 1536);
    softmax_pv(s00,s01,s02,s03, true, g, m0v, lacc0, o00, o01, A0lo, A0hi, A1lo, A1hi, ones);
    softmax_pv(s10,s11,s12,s13, true, g, m1v, lacc1, o10, o11, A0lo, A0hi, A1lo, A1hi, ones);
  }
  const size_t ob0 = (size_t)(sp*NH + h)*NQ;
  const int qw0 = q0 + c;
  if (qw0 < NQ) {
    const size_t b = (ob0 + qw0)*DH;
    #pragma unroll
    for (int r=0;r<4;++r) {
      opart[b +      g*4 + r] = f2bf(o00[r]);
      opart[b + 16 + g*4 + r] = f2bf(o01[r]);
    }
    if (g == 0) { mlp[(ob0 + qw0)*2] = m0v; mlp[(ob0 + qw0)*2+1] = lacc0[0]; }
  }
  const int qw1 = q0 + 16 + c;
  if (qw1 < NQ) {
    const size_t b = (ob0 + qw1)*DH;
    #pragma unroll
    for (int r=0;r<4;++r) {
      opart[b +      g*4 + r] = f2bf(o10[r]);
      opart[b + 16 + g*4 + r] = f2bf(o11[r]);
    }
    if (g == 0) { mlp[(ob0 + qw1)*2] = m1v; mlp[(ob0 + qw1)*2+1] = lacc1[0]; }
  }
}

// ---------------- row LayerNorm (final LN only) ----------------
__global__ __launch_bounds__(256) void k_ln(
    const float* __restrict__ x, const float* __restrict__ g,
    const float* __restrict__ b, const float* __restrict__ post_res,
    float* __restrict__ out)
{
  const int row = blockIdx.x, c = threadIdx.x;
  const size_t idx = (size_t)row*CDIM + c;
  const float v = x[idx];
  __shared__ float red[4];
  float s = v;
  #pragma unroll
  for (int m = 1; m < 64; m <<= 1) s += __shfl_xor(s, m);
  if ((c & 63) == 0) red[c >> 6] = s;
  __syncthreads();
  const float mean = (red[0]+red[1]+red[2]+red[3]) * (1.f/256.f);
  const float dv = v - mean;
  __syncthreads();
  float s2 = dv*dv;
  #pragma unroll
  for (int m = 1; m < 64; m <<= 1) s2 += __shfl_xor(s2, m);
  if ((c & 63) == 0) red[c >> 6] = s2;
  __syncthreads();
  const float var = (red[0]+red[1]+red[2]+red[3]) * (1.f/256.f);
  float o = dv * rsqrtf(var + 1e-5f) * g[c] + b[c];
  if (post_res) o += post_res[idx];
  out[idx] = o;
}

// ---- fused LN1 + attn_w GEMV + softmax(24) + sampling + agg (round-16 proven) ----
__global__ __launch_bounds__(256) void k_sample_agg(
    const float* __restrict__ tmp1, const float* __restrict__ n1g,
    const float* __restrict__ n1b, float* __restrict__ q1,
    const unsigned short* __restrict__ imgT,
    const float* __restrict__ l2i, const float* __restrict__ awW,
    const float* __restrict__ awb, float* __restrict__ agg)
{
  const int q = blockIdx.x, tid = threadIdx.x;
  __shared__ float qrow[256];
  __shared__ float red[4];
  __shared__ float wl[24];
  __shared__ float fwx[24], fwy[24];
  __shared__ int iv[24], ix[24], iy[24];
  // ---- LN1 (proven k_ln pattern) ----
  const size_t idx = (size_t)q*CDIM + tid;
  const float v = tmp1[idx];
  float s = v;
  #pragma unroll
  for (int m = 1; m < 64; m <<= 1) s += __shfl_xor(s, m);
  if ((tid & 63) == 0) red[tid >> 6] = s;
  __syncthreads();
  const float mean = (red[0]+red[1]+red[2]+red[3]) * (1.f/256.f);
  const float dv = v - mean;
  __syncthreads();
  float s2 = dv*dv;
  #pragma unroll
  for (int m = 1; m < 64; m <<= 1) s2 += __shfl_xor(s2, m);
  if ((tid & 63) == 0) red[tid >> 6] = s2;
  __syncthreads();
  const float var = (red[0]+red[1]+red[2]+red[3]) * (1.f/256.f);
  const float o = dv * rsqrtf(var + 1e-5f) * n1g[tid] + n1b[tid];
  q1[idx] = o;                 // residual input for the scaW GEMM
  qrow[tid] = o;
  __syncthreads();
  // ---- proven sample_agg body ----
  if (tid < 192) {
    const int e = tid >> 3, s2b = tid & 7;
    float acc = 0.f;
    for (int c = s2b; c < 256; c += 8) acc += qrow[c]*awW[e*256 + c];
    acc += __shfl_xor(acc,1);
    acc += __shfl_xor(acc,2);
    acc += __shfl_xor(acc,4);
    if (s2b == 0) wl[e] = acc + awb[e];
  }
  if (tid < 24) {
    const int e = tid, n = e >> 2, z = e & 3;
    const int iyq = q / 50, jxq = q % 50;
    const float rx = (jxq + 0.5f)*(1.f/50.f);
    const float ry = (iyq + 0.5f)*(1.f/50.f);
    const float rz = (z + 0.5f)*0.25f;
    const float X = rx*102.4f - 51.2f;
    const float Y = ry*102.4f - 51.2f;
    const float Z = rz*8.f - 5.f;
    const float* L = l2i + n*16;
    const float cx = L[0]*X + L[1]*Y + L[2]*Z  + L[3];
    const float cy = L[4]*X + L[5]*Y + L[6]*Z  + L[7];
    const float cd = L[8]*X + L[9]*Y + L[10]*Z + L[11];
    const float dn = fmaxf(cd, 1e-5f);
    const float u = cx/dn, vv = cy/dn;
    const float gx = (u*(1.f/49.f) - 0.5f)*2.f;
    const float gy = (vv*(1.f/27.f) - 0.5f)*2.f;
    const int ok = (cd > 1e-5f) && (gx > -1.f) && (gx < 1.f) && (gy > -1.f) && (gy < 1.f);
    const float xf = ((gx + 1.f)*50.f - 1.f)*0.5f;
    const float yf = ((gy + 1.f)*28.f - 1.f)*0.5f;
    const float x0f = floorf(xf), y0f = floorf(yf);
    iv[e] = ok; ix[e] = (int)x0f; iy[e] = (int)y0f;
    fwx[e] = xf - x0f; fwy[e] = yf - y0f;
  }
  __syncthreads();
  float mx = -INFINITY;
  #pragma unroll
  for (int e = 0; e < 24; ++e) mx = fmaxf(mx, wl[e]);
  float se = 0.f;
  #pragma unroll
  for (int e = 0; e < 24; ++e) se += __expf(wl[e]-mx);
  const float inv = 1.f/se;
  const int c = tid;
  float acc = 0.f;
  #pragma unroll
  for (int e = 0; e < 24; ++e) {
    if (!iv[e]) continue;
    const float w = __expf(wl[e]-mx)*inv;
    const int n = e >> 2;
    const int x0 = ix[e], y0 = iy[e];
    const float wx = fwx[e], wy = fwy[e];
    const size_t base = (size_t)(n*28)*50;
    float v00 = (x0  >=0 && x0  <50 && y0  >=0 && y0  <28) ? bf2f(imgT[((base + (size_t)y0*50     + x0  ))*CDIM + c]) : 0.f;
    float v10 = (x0+1>=0 && x0+1<50 && y0  >=0 && y0  <28) ? bf2f(imgT[((base + (size_t)y0*50     + x0+1))*CDIM + c]) : 0.f;
    float v01 = (x0  >=0 && x0  <50 && y0+1>=0 && y0+1<28) ? bf2f(imgT[((base + (size_t)(y0+1)*50 + x0  ))*CDIM + c]) : 0.f;
    float v11 = (x0+1>=0 && x0+1<50 && y0+1>=0 && y0+1<28) ? bf2f(imgT[((base + (size_t)(y0+1)*50 + x0+1))*CDIM + c]) : 0.f;
    acc += w * ((v00*(1.f-wx) + v10*wx)*(1.f-wy) + (v01*(1.f-wx) + v11*wx)*wy);
  }
  agg[(size_t)q*CDIM + c] = acc;
}

// ---------------- launcher ----------------
extern "C" void kernel_launch(void* const* d_in, const int* in_sizes, int n_in,
                              void* d_out, int out_size, void* d_ws, size_t ws_size,
                              hipStream_t stream)
{
  const float* query = (const float*)d_in[0];
  const float* prev  = (const float*)d_in[1];
  const float* img   = (const float*)d_in[2];
  const float* ego   = (const float*)d_in[3];
  const float* l2i   = (const float*)d_in[4];
  const float* awW   = (const float*)d_in[5];
  const float* awb   = (const float*)d_in[6];
  const float* scab  = (const float*)d_in[8];
  const float* inb   = (const float*)d_in[10];
  const float* mob   = (const float*)d_in[12];
  const float* n1g   = (const float*)d_in[13];
  const float* n1b   = (const float*)d_in[14];
  const float* fb1   = (const float*)d_in[16];
  const float* fb2   = (const float*)d_in[18];
  const float* n2g   = (const float*)d_in[19];
  const float* n2b   = (const float*)d_in[20];
  float* out = (float*)d_out;
  float* ws  = (float*)d_ws;

  // ---- workspace layout (float offsets, round-15 proven); total 8,505,472 f = 34.0 MB ----
  float* kv    = ws;                        // [5000,256] f32   [0,        1280000)
  short* Qbf   = (short*)(ws + 1280000);    // [2500,256] bf16  [1280000,  1600000)
  short* Kbf   = (short*)(ws + 1600000);    // [5000,256] bf16  [1600000,  2240000)
  short* VbfT  = (short*)(ws + 2240000);    // [256,5000] bf16  [2240000,  2880000)
  short* Vf    = (short*)(ws + 2880000);    // 1,310,720 bf16   [2880000,  3535360)
  short* opart = (short*)(ws + 3535360);    // [10,8,2500,32]   [3535360,  6735360)
  float* mlp   = ws + 6735360;              // [10,8,2500,2]    [6735360,  7135360)
  short* wf    = (short*)(ws + 7135360);    // 589,824 bf16     [7135360,  7430272)
  unsigned short* imgT = (unsigned short*)(ws + 7430272); // [6,28,50,256] [7430272, 8505472)
  // phase B reuse (disjoint per dispatch; opart/mlp live until moW GEMM):
  float* tmp1  = ws;                        // [0,       640000)  (kv dead)
  float* q1    = ws +  640000;              // [640000, 1280000)  (kv dead)
  float* aggb  = ws + 1280000;              // [1280000,1920000)  (Qbf/Kbf-head dead)
  float* q2    = ws + 1920000;              // [1920000,2560000)  (Kbf-tail/VbfT-head dead)
  float* hbuf  = ws + 2560000;              // [2560000,3840000)  (VbfT/Vf/opart-head dead)
  float* h2    = ws + 3840000;              // [3840000,4480000)  (opart dead)

  const float qscale = 0.2550727452794943f;  // (1/sqrt(32)) * log2(e)

  k_prep<<<5456, 256, 0, stream>>>(query, prev, ego, kv, img, imgT,
                                   (const float*)d_in[9], (const float*)d_in[11],
                                   (const float*)d_in[7], (const float*)d_in[15],
                                   (const float*)d_in[17], wf);
  k_gemm_qkv<<<dim3(12,157), 256, 0, stream>>>(kv, wf, inb, Qbf, Kbf, VbfT, qscale);
  k_repack_v<<<5120, 256, 0, stream>>>(VbfT, Vf);
  k_flash6<<<79*80, 64, 0, stream>>>(Qbf, Kbf, Vf, opart, mlp);
  // moW GEMM with A = combine(opart, mlp) fused into staging; res = query
  k_gemm<<<dim3(4,79), 256, 0, stream>>>(nullptr, wf + 196608, mob, query, tmp1, nullptr,
                                         opart, mlp, NQ, 256, 256, 0, 0, 1, 1.0f);
  // fused LN1 + sampling/aggregation (writes q1 for residual, aggb)
  k_sample_agg<<<NQ, 256, 0, stream>>>(tmp1, n1g, n1b, q1, imgT, l2i, awW, awb, aggb);
  k_gemm<<<dim3(4,79), 256, 0, stream>>>(aggb, wf + 262144, scab, q1, q2, nullptr,
                                         nullptr, nullptr, NQ, 256, 256, 0, 0, 0, 1.0f);
  k_gemm<<<dim3(8,79), 256, 0, stream>>>(q2, wf + 327680, fb1, nullptr, hbuf, nullptr,
                                         nullptr, nullptr, NQ, 512, 256, 1, 0, 0, 1.0f);
  k_gemm<<<dim3(4,79), 256, 0, stream>>>(hbuf, wf + 458752, fb2, nullptr, h2, nullptr,
                                         nullptr, nullptr, NQ, 256, 512, 0, 0, 0, 1.0f);
  k_ln<<<NQ, 256, 0, stream>>>(h2, n2g, n2b, q2, out);
}